// Round 1
// baseline (1053.807 us; speedup 1.0000x reference)
//
#include <hip/hip_runtime.h>
#include <hip/hip_bf16.h>

#define Nn 20000
#define Bg 8
#define Eg 320000
#define FDim 128
#define Dd 64
#define Hh 128

__device__ __forceinline__ float bcastf(float v, int l) {
  return __int_as_float(__builtin_amdgcn_readlane(__float_as_int(v), l));
}

// K1: base = node_features @ w_n2l + bias_n2l   [N,128]@[128,64]
__global__ __launch_bounds__(256) void k_base(const float* __restrict__ x,
                                              const float* __restrict__ W,
                                              const float* __restrict__ b,
                                              float* __restrict__ base) {
  __shared__ float Wl[FDim * Dd];   // 32 KB
  __shared__ float xl[4][FDim];
  int t = threadIdx.x;
  for (int i = t; i < FDim * Dd; i += 256) Wl[i] = W[i];
  __syncthreads();
  int wv = t >> 6, lane = t & 63;
  int row = blockIdx.x * 4 + wv;
  if (row < Nn) {
    xl[wv][lane] = x[row * FDim + lane];
    xl[wv][64 + lane] = x[row * FDim + 64 + lane];
    float acc = b[lane];
#pragma unroll
    for (int k = 0; k < FDim; ++k) acc = fmaf(xl[wv][k], Wl[k * Dd + lane], acc);
    base[row * Dd + lane] = acc;
  }
}

// K2: per-graph dst-degree histogram
__global__ void k_hist(const int* __restrict__ dst, int* __restrict__ deg) {
  int g = blockIdx.y;
  int e = blockIdx.x * 256 + threadIdx.x;
  if (e < Eg) atomicAdd(&deg[g * Nn + dst[(size_t)g * Eg + e]], 1);
}

// K3: exclusive prefix-sum of deg -> offs (one block per graph)
__global__ __launch_bounds__(1024) void k_scan(const int* __restrict__ deg,
                                               int* __restrict__ offs) {
  int g = blockIdx.x;
  const int* dp = deg + g * Nn;
  int* op = offs + g * Nn;
  __shared__ int buf[1024];
  __shared__ int carry;
  if (threadIdx.x == 0) carry = 0;
  __syncthreads();
  for (int b0 = 0; b0 < Nn; b0 += 1024) {
    int idx = b0 + threadIdx.x;
    int v = (idx < Nn) ? dp[idx] : 0;
    buf[threadIdx.x] = v;
    __syncthreads();
    for (int off = 1; off < 1024; off <<= 1) {
      int tv = (threadIdx.x >= off) ? buf[threadIdx.x - off] : 0;
      __syncthreads();
      buf[threadIdx.x] += tv;
      __syncthreads();
    }
    int incl = buf[threadIdx.x];
    int cc = carry;
    if (idx < Nn) op[idx] = cc + incl - v;  // exclusive
    __syncthreads();
    if (threadIdx.x == 1023) carry = cc + incl;
    __syncthreads();
  }
}

// K4: counting-sort scatter (offs becomes END pointer after this)
__global__ void k_scatter(const int* __restrict__ src, const int* __restrict__ dst,
                          const float* __restrict__ w, int* __restrict__ offs,
                          int* __restrict__ ssrc, float* __restrict__ sw) {
  int g = blockIdx.y;
  int e = blockIdx.x * 256 + threadIdx.x;
  if (e < Eg) {
    size_t be = (size_t)g * Eg + e;
    int d = dst[be];
    int pos = atomicAdd(&offs[g * Nn + d], 1);
    ssrc[(size_t)g * Eg + pos] = src[be];
    sw[(size_t)g * Eg + pos] = w[be];
  }
}

// K5: h0[g] = relu(base + onehot(picked[g])*bias_picked)
__global__ void k_init(const float* __restrict__ base, const float* __restrict__ biasp,
                       const int* __restrict__ picked, float* __restrict__ h0) {
  size_t tot = (size_t)Bg * Nn * 16;  // float4 granules
  for (size_t idx = (size_t)blockIdx.x * 256 + threadIdx.x; idx < tot;
       idx += (size_t)gridDim.x * 256) {
    int g = (int)(idx / (Nn * 16));
    int rem = (int)(idx - (size_t)g * Nn * 16);
    int i = rem >> 4, q = rem & 15;
    float4 v = *(const float4*)&base[i * Dd + q * 4];
    if (i == picked[g]) {
      float4 bp = *(const float4*)&biasp[q * 4];
      v.x += bp.x; v.y += bp.y; v.z += bp.z; v.w += bp.w;
    }
    v.x = fmaxf(v.x, 0.f); v.y = fmaxf(v.y, 0.f);
    v.z = fmaxf(v.z, 0.f); v.w = fmaxf(v.w, 0.f);
    *(float4*)&h0[(size_t)g * Nn * Dd + (size_t)i * Dd + q * 4] = v;
  }
}

// K6: fused SpMM (CSR gather) + conv matvec + bias + input_message + relu
__global__ __launch_bounds__(256) void k_level(
    const float* __restrict__ hin, float* __restrict__ hout,
    const float* __restrict__ base, const float* __restrict__ convW,
    const float* __restrict__ convb, const float* __restrict__ biasp,
    const int* __restrict__ picked, const int* __restrict__ deg,
    const int* __restrict__ offs, const int* __restrict__ ssrc,
    const float* __restrict__ sw) {
  __shared__ float Wl[Dd * Dd];  // 16 KB
  int t = threadIdx.x;
  for (int i = t; i < Dd * Dd; i += 256) Wl[i] = convW[i];
  __syncthreads();
  int wv = t >> 6, lane = t & 63;
  float wcol[Dd];  // conv_W column `lane` in registers
#pragma unroll
  for (int d = 0; d < Dd; ++d) wcol[d] = Wl[d * Dd + lane];
  float cb = convb[lane];
  float bp = biasp[lane];
  for (int row = blockIdx.x * 4 + wv; row < Bg * Nn; row += gridDim.x * 4) {
    int g = row / Nn;
    int i = row - g * Nn;
    int end = offs[g * Nn + i];
    int dg = deg[g * Nn + i];
    const float* hg = hin + (size_t)g * Nn * Dd;
    const int* sp = ssrc + (size_t)g * Eg;
    const float* wp = sw + (size_t)g * Eg;
    float acc = 0.f;
    int e = end - dg;
    for (; e + 2 <= end; e += 2) {
      int s0 = sp[e], s1 = sp[e + 1];
      float w0 = wp[e], w1 = wp[e + 1];
      float v0 = hg[(size_t)s0 * Dd + lane];
      float v1 = hg[(size_t)s1 * Dd + lane];
      acc = fmaf(v0, w0, acc);
      acc = fmaf(v1, w1, acc);
    }
    if (e < end) acc = fmaf(hg[(size_t)sp[e] * Dd + lane], wp[e], acc);
    float out = base[i * Dd + lane] + cb;
    if (i == picked[g]) out += bp;
#pragma unroll
    for (int d = 0; d < Dd; ++d) out = fmaf(bcastf(acc, d), wcol[d], out);
    out = fmaxf(out, 0.f);
    hout[(size_t)g * Nn * Dd + (size_t)i * Dd + lane] = out;
  }
}

// K7: per-graph column sums of h (for graph mean)
__global__ void k_gsum(const float* __restrict__ h, float* __restrict__ gsum) {
  int g = blockIdx.y;
  int wv = threadIdx.x >> 6, lane = threadIdx.x & 63;
  __shared__ float red[4][Dd];
  float acc = 0.f;
  const float* hg = h + (size_t)g * Nn * Dd;
  for (int r = blockIdx.x * 4 + wv; r < Nn; r += gridDim.x * 4)
    acc += hg[(size_t)r * Dd + lane];
  red[wv][lane] = acc;
  __syncthreads();
  if (wv == 0) {
    float s = red[0][lane] + red[1][lane] + red[2][lane] + red[3][lane];
    atomicAdd(&gsum[g * Dd + lane], s);
  }
}

// K8: per-graph constants: cvec = g_embed@lin1_W[64:] + lin1_b ; u = lout_W@t ; c = lout_b.t
__global__ __launch_bounds__(128) void k_prep(
    const float* __restrict__ h, const float* __restrict__ gsum,
    const int* __restrict__ tgt, const float* __restrict__ lin1W,
    const float* __restrict__ lin1b, const float* __restrict__ loutW,
    const float* __restrict__ loutb, float* __restrict__ cvec,
    float* __restrict__ uvec, float* __restrict__ cscal) {
  int g = blockIdx.x;
  int k = threadIdx.x;
  __shared__ float tv[Dd], ge[Dd];
  if (k < Dd) {
    tv[k] = h[(size_t)g * Nn * Dd + (size_t)tgt[g] * Dd + k];
    ge[k] = gsum[g * Dd + k] * (1.0f / Nn);
  }
  __syncthreads();
  float cv = lin1b[k];
#pragma unroll 8
  for (int d = 0; d < Dd; ++d) cv = fmaf(ge[d], lin1W[(Dd + d) * Hh + k], cv);
  cvec[g * Hh + k] = cv;
  float uu = 0.f;
#pragma unroll 8
  for (int j = 0; j < Dd; ++j) uu = fmaf(loutW[k * Dd + j], tv[j], uu);
  uvec[g * Hh + k] = uu;
  if (k == 0) {
    float c = 0.f;
    for (int j = 0; j < Dd; ++j) c += loutb[j] * tv[j];
    cscal[g] = c;
  }
}

// K9: q[g,i] = sum_k relu(h_i . W1[:,k] + cvec[k]) * u[k] + c  (2 rows per wave)
__global__ __launch_bounds__(256) void k_final(
    const float* __restrict__ h, const float* __restrict__ lin1W,
    const float* __restrict__ cvec, const float* __restrict__ uvec,
    const float* __restrict__ cscal, float* __restrict__ out) {
  __shared__ float Wl[Dd * Hh];  // 32 KB: lin1_W rows 0..63
  int t = threadIdx.x;
  for (int i = t; i < Dd * Hh; i += 256) Wl[i] = lin1W[i];
  __syncthreads();
  int wv = t >> 6, lane = t & 63;
  int tot = Bg * Nn / 2;  // row pairs (never straddle a graph: N even)
  for (int p = blockIdx.x * 4 + wv; p < tot; p += gridDim.x * 4) {
    int row0 = p * 2;
    int g = row0 / Nn;
    int i0 = row0 - g * Nn;
    const float* hr = h + (size_t)g * Nn * Dd + (size_t)i0 * Dd;
    float h0v = hr[lane], h1v = hr[Dd + lane];
    float c0 = cvec[g * Hh + lane], c1 = cvec[g * Hh + 64 + lane];
    float u0 = uvec[g * Hh + lane], u1 = uvec[g * Hh + 64 + lane];
    float z00 = c0, z01 = c1, z10 = c0, z11 = c1;
#pragma unroll
    for (int d = 0; d < Dd; ++d) {
      float w0 = Wl[d * Hh + lane], w1 = Wl[d * Hh + 64 + lane];
      float hv0 = bcastf(h0v, d), hv1 = bcastf(h1v, d);
      z00 = fmaf(hv0, w0, z00);
      z01 = fmaf(hv0, w1, z01);
      z10 = fmaf(hv1, w0, z10);
      z11 = fmaf(hv1, w1, z11);
    }
    float s0 = fmaxf(z00, 0.f) * u0 + fmaxf(z01, 0.f) * u1;
    float s1 = fmaxf(z10, 0.f) * u0 + fmaxf(z11, 0.f) * u1;
#pragma unroll
    for (int off = 32; off; off >>= 1) {
      s0 += __shfl_xor(s0, off, 64);
      s1 += __shfl_xor(s1, off, 64);
    }
    if (lane == 0) {
      float cc = cscal[g];
      out[row0] = s0 + cc;
      out[row0 + 1] = s1 + cc;
    }
  }
}

extern "C" void kernel_launch(void* const* d_in, const int* in_sizes, int n_in,
                              void* d_out, int out_size, void* d_ws, size_t ws_size,
                              hipStream_t stream) {
  const float* node_features = (const float*)d_in[0];
  const float* w_n2l        = (const float*)d_in[1];
  const float* bias_n2l     = (const float*)d_in[2];
  const float* bias_picked  = (const float*)d_in[3];
  const float* conv_W       = (const float*)d_in[4];
  const float* conv_b       = (const float*)d_in[5];
  const float* lin1_W       = (const float*)d_in[6];
  const float* lin1_b       = (const float*)d_in[7];
  const float* lout_W       = (const float*)d_in[8];
  const float* lout_b       = (const float*)d_in[9];
  const float* edge_w       = (const float*)d_in[10];
  const int*   edges_src    = (const int*)d_in[11];
  const int*   edges_dst    = (const int*)d_in[12];
  const int*   target_nodes = (const int*)d_in[13];
  const int*   picked_nodes = (const int*)d_in[14];
  float* q_out = (float*)d_out;

  // workspace layout (floats unless noted)
  float* base = (float*)d_ws;                          // N*D
  float* h0   = base + (size_t)Nn * Dd;                // B*N*D
  float* h1   = h0 + (size_t)Bg * Nn * Dd;             // B*N*D
  int*   deg  = (int*)(h1 + (size_t)Bg * Nn * Dd);     // B*N
  int*   offs = deg + (size_t)Bg * Nn;                 // B*N
  int*   ssrc = offs + (size_t)Bg * Nn;                // B*E
  float* sw   = (float*)(ssrc + (size_t)Bg * Eg);      // B*E
  float* gsum = sw + (size_t)Bg * Eg;                  // B*64
  float* cvec = gsum + Bg * Dd;                        // B*128
  float* uvec = cvec + Bg * Hh;                        // B*128
  float* csc  = uvec + Bg * Hh;                        // B

  hipMemsetAsync(deg, 0, (size_t)Bg * Nn * sizeof(int), stream);
  hipMemsetAsync(gsum, 0, (size_t)Bg * Dd * sizeof(float), stream);

  k_base<<<(Nn + 3) / 4, 256, 0, stream>>>(node_features, w_n2l, bias_n2l, base);
  k_hist<<<dim3(Eg / 256, Bg), 256, 0, stream>>>(edges_dst, deg);
  k_scan<<<Bg, 1024, 0, stream>>>(deg, offs);
  k_scatter<<<dim3(Eg / 256, Bg), 256, 0, stream>>>(edges_src, edges_dst, edge_w,
                                                    offs, ssrc, sw);
  k_init<<<2048, 256, 0, stream>>>(base, bias_picked, picked_nodes, h0);
  k_level<<<2048, 256, 0, stream>>>(h0, h1, base, conv_W, conv_b, bias_picked,
                                    picked_nodes, deg, offs, ssrc, sw);
  k_level<<<2048, 256, 0, stream>>>(h1, h0, base, conv_W, conv_b, bias_picked,
                                    picked_nodes, deg, offs, ssrc, sw);
  k_gsum<<<dim3(32, Bg), 256, 0, stream>>>(h0, gsum);
  k_prep<<<Bg, 128, 0, stream>>>(h0, gsum, target_nodes, lin1_W, lin1_b, lout_W,
                                 lout_b, cvec, uvec, csc);
  k_final<<<2048, 256, 0, stream>>>(h0, lin1_W, cvec, uvec, csc, q_out);
}

// Round 3
// 821.263 us; speedup vs baseline: 1.2832x; 1.2832x over previous
//
#include <hip/hip_runtime.h>
#include <hip/hip_bf16.h>

#define Nn 20000
#define Bg 8
#define Eg 320000
#define FDim 128
#define Dd 64
#define Hh 128

__device__ __forceinline__ float bcastf(float v, int l) {
  return __int_as_float(__builtin_amdgcn_readlane(__float_as_int(v), l));
}

// K1: base = node_features @ w_n2l + bias_n2l   [N,128]@[128,64], grid-stride
__global__ __launch_bounds__(256) void k_base(const float* __restrict__ x,
                                              const float* __restrict__ W,
                                              const float* __restrict__ b,
                                              float* __restrict__ base) {
  __shared__ float Wl[FDim * Dd];   // 32 KB
  int t = threadIdx.x;
  for (int i = t; i < FDim * Dd; i += 256) Wl[i] = W[i];
  __syncthreads();
  int wv = t >> 6, lane = t & 63;
  float bias = b[lane];
  for (int row = blockIdx.x * 4 + wv; row < Nn; row += gridDim.x * 4) {
    float x0 = x[row * FDim + lane];
    float x1 = x[row * FDim + 64 + lane];
    float acc = bias;
#pragma unroll
    for (int k = 0; k < 64; ++k) acc = fmaf(bcastf(x0, k), Wl[k * Dd + lane], acc);
#pragma unroll
    for (int k = 0; k < 64; ++k) acc = fmaf(bcastf(x1, k), Wl[(64 + k) * Dd + lane], acc);
    base[row * Dd + lane] = acc;
  }
}

// K2: per-graph dst-degree histogram
__global__ void k_hist(const int* __restrict__ dst, int* __restrict__ deg) {
  int g = blockIdx.y;
  int e = blockIdx.x * 256 + threadIdx.x;
  if (e < Eg) atomicAdd(&deg[g * Nn + dst[(size_t)g * Eg + e]], 1);
}

// K3: exclusive prefix-sum of deg -> offs (one block per graph)
__global__ __launch_bounds__(1024) void k_scan(const int* __restrict__ deg,
                                               int* __restrict__ offs) {
  int g = blockIdx.x;
  const int* dp = deg + g * Nn;
  int* op = offs + g * Nn;
  __shared__ int buf[1024];
  __shared__ int carry;
  if (threadIdx.x == 0) carry = 0;
  __syncthreads();
  for (int b0 = 0; b0 < Nn; b0 += 1024) {
    int idx = b0 + threadIdx.x;
    int v = (idx < Nn) ? dp[idx] : 0;
    buf[threadIdx.x] = v;
    __syncthreads();
    for (int off = 1; off < 1024; off <<= 1) {
      int tv = (threadIdx.x >= off) ? buf[threadIdx.x - off] : 0;
      __syncthreads();
      buf[threadIdx.x] += tv;
      __syncthreads();
    }
    int incl = buf[threadIdx.x];
    int cc = carry;
    if (idx < Nn) op[idx] = cc + incl - v;  // exclusive
    __syncthreads();
    if (threadIdx.x == 1023) carry = cc + incl;
    __syncthreads();
  }
}

// K4: counting-sort scatter of src only (offs becomes END pointer after this).
// Weight not stored: after dst-sort, w within a row is constant = 1/deg.
__global__ void k_scatter(const int* __restrict__ src, const int* __restrict__ dst,
                          int* __restrict__ offs, int* __restrict__ ssrc) {
  int g = blockIdx.y;
  int e = blockIdx.x * 256 + threadIdx.x;
  if (e < Eg) {
    size_t be = (size_t)g * Eg + e;
    int d = dst[be];
    int pos = atomicAdd(&offs[g * Nn + d], 1);
    ssrc[(size_t)g * Eg + pos] = src[be];
  }
}

// K5: fused SpMM (CSR gather, 8 outstanding loads) + conv matvec + relu.
// LV1: gather from shared `base` applying relu + picked-bias on the fly.
template <bool LV1>
__global__ __launch_bounds__(256) void k_level(
    const float* __restrict__ hin, float* __restrict__ hout,
    const float* __restrict__ base, const float* __restrict__ convW,
    const float* __restrict__ convb, const float* __restrict__ biasp,
    const int* __restrict__ picked, const int* __restrict__ deg,
    const int* __restrict__ offs, const int* __restrict__ ssrc) {
  __shared__ float Wl[Dd * Dd];  // 16 KB
  int t = threadIdx.x;
  for (int i = t; i < Dd * Dd; i += 256) Wl[i] = convW[i];
  __syncthreads();
  int wv = t >> 6, lane = t & 63;
  float cb = convb[lane];
  float bp = biasp[lane];
  for (int row = blockIdx.x * 4 + wv; row < Bg * Nn; row += gridDim.x * 4) {
    int g = row / Nn;
    int i = row - g * Nn;
    int end = offs[g * Nn + i];
    int dg = deg[g * Nn + i];
    int beg = end - dg;
    int pick = picked[g];
    const int* sp = ssrc + (size_t)g * Eg;
    const float* sb = LV1 ? base : (hin + (size_t)g * Nn * Dd);

    auto GATHER = [&](int s) -> float {
      float v = sb[(size_t)s * Dd + lane];
      if (LV1) {
        if (s == pick) v += bp;
        v = fmaxf(v, 0.f);
      }
      return v;
    };

    float acc = 0.f;
    if (dg <= 64) {
      int sv = 0;
      if (beg + lane < end) sv = sp[beg + lane];  // one coalesced index load
      int j = 0;
      for (; j + 8 <= dg; j += 8) {
        int s0 = __builtin_amdgcn_readlane(sv, j + 0);
        int s1 = __builtin_amdgcn_readlane(sv, j + 1);
        int s2 = __builtin_amdgcn_readlane(sv, j + 2);
        int s3 = __builtin_amdgcn_readlane(sv, j + 3);
        int s4 = __builtin_amdgcn_readlane(sv, j + 4);
        int s5 = __builtin_amdgcn_readlane(sv, j + 5);
        int s6 = __builtin_amdgcn_readlane(sv, j + 6);
        int s7 = __builtin_amdgcn_readlane(sv, j + 7);
        float v0 = GATHER(s0), v1 = GATHER(s1), v2 = GATHER(s2), v3 = GATHER(s3);
        float v4 = GATHER(s4), v5 = GATHER(s5), v6 = GATHER(s6), v7 = GATHER(s7);
        acc += (((v0 + v1) + (v2 + v3)) + ((v4 + v5) + (v6 + v7)));
      }
      for (; j < dg; ++j) acc += GATHER(__builtin_amdgcn_readlane(sv, j));
    } else {  // degree > 64 fallback (statistically never at avg deg 16)
      for (int e = beg; e < end; ++e) acc += GATHER(sp[e]);
    }
    float wsc = dg ? 1.0f / (float)dg : 0.f;
    acc *= wsc;

    float out = base[(size_t)i * Dd + lane] + cb;
    if (i == pick) out += bp;
#pragma unroll
    for (int d = 0; d < Dd; ++d) out = fmaf(bcastf(acc, d), Wl[d * Dd + lane], out);
    out = fmaxf(out, 0.f);
    hout[(size_t)g * Nn * Dd + (size_t)i * Dd + lane] = out;
  }
}

// K6: per-graph column sums of h (for graph mean)
__global__ void k_gsum(const float* __restrict__ h, float* __restrict__ gsum) {
  int g = blockIdx.y;
  int wv = threadIdx.x >> 6, lane = threadIdx.x & 63;
  __shared__ float red[4][Dd];
  float acc = 0.f;
  const float* hg = h + (size_t)g * Nn * Dd;
  for (int r = blockIdx.x * 4 + wv; r < Nn; r += gridDim.x * 4)
    acc += hg[(size_t)r * Dd + lane];
  red[wv][lane] = acc;
  __syncthreads();
  if (wv == 0) {
    float s = red[0][lane] + red[1][lane] + red[2][lane] + red[3][lane];
    atomicAdd(&gsum[g * Dd + lane], s);
  }
}

// K7: per-graph constants: cvec = g_embed@lin1_W[64:] + lin1_b ; u = lout_W@t ; c = lout_b.t
__global__ __launch_bounds__(128) void k_prep(
    const float* __restrict__ h, const float* __restrict__ gsum,
    const int* __restrict__ tgt, const float* __restrict__ lin1W,
    const float* __restrict__ lin1b, const float* __restrict__ loutW,
    const float* __restrict__ loutb, float* __restrict__ cvec,
    float* __restrict__ uvec, float* __restrict__ cscal) {
  int g = blockIdx.x;
  int k = threadIdx.x;
  __shared__ float tv[Dd], ge[Dd];
  if (k < Dd) {
    tv[k] = h[(size_t)g * Nn * Dd + (size_t)tgt[g] * Dd + k];
    ge[k] = gsum[g * Dd + k] * (1.0f / Nn);
  }
  __syncthreads();
  float cv = lin1b[k];
#pragma unroll 8
  for (int d = 0; d < Dd; ++d) cv = fmaf(ge[d], lin1W[(Dd + d) * Hh + k], cv);
  cvec[g * Hh + k] = cv;
  float uu = 0.f;
#pragma unroll 8
  for (int j = 0; j < Dd; ++j) uu = fmaf(loutW[k * Dd + j], tv[j], uu);
  uvec[g * Hh + k] = uu;
  if (k == 0) {
    float c = 0.f;
    for (int j = 0; j < Dd; ++j) c += loutb[j] * tv[j];
    cscal[g] = c;
  }
}

// K8: q[g,i] = sum_k relu(h_i . W1[:,k] + cvec[k]) * u[k] + c   (4 rows per wave)
__global__ __launch_bounds__(256) void k_final(
    const float* __restrict__ h, const float* __restrict__ lin1W,
    const float* __restrict__ cvec, const float* __restrict__ uvec,
    const float* __restrict__ cscal, float* __restrict__ out) {
  __shared__ float Wl[Dd * Hh];  // 32 KB: lin1_W rows 0..63
  int t = threadIdx.x;
  for (int i = t; i < Dd * Hh; i += 256) Wl[i] = lin1W[i];
  __syncthreads();
  int wv = t >> 6, lane = t & 63;
  int tot = Bg * Nn / 4;  // quads never straddle a graph (N % 4 == 0)
  for (int p = blockIdx.x * 4 + wv; p < tot; p += gridDim.x * 4) {
    int row0 = p * 4;
    int g = row0 / Nn;
    int i0 = row0 - g * Nn;
    const float* hr = h + (size_t)g * Nn * Dd + (size_t)i0 * Dd;
    float ha = hr[lane], hb = hr[64 + lane], hc = hr[128 + lane], hd = hr[192 + lane];
    float c0 = cvec[g * Hh + lane], c1 = cvec[g * Hh + 64 + lane];
    float u0 = uvec[g * Hh + lane], u1 = uvec[g * Hh + 64 + lane];
    float za0 = c0, za1 = c1, zb0 = c0, zb1 = c1;
    float zc0 = c0, zc1 = c1, zd0 = c0, zd1 = c1;
#pragma unroll
    for (int d = 0; d < Dd; ++d) {
      float w0 = Wl[d * Hh + lane], w1 = Wl[d * Hh + 64 + lane];
      float a = bcastf(ha, d), b2 = bcastf(hb, d);
      float c2 = bcastf(hc, d), d2 = bcastf(hd, d);
      za0 = fmaf(a, w0, za0);  za1 = fmaf(a, w1, za1);
      zb0 = fmaf(b2, w0, zb0); zb1 = fmaf(b2, w1, zb1);
      zc0 = fmaf(c2, w0, zc0); zc1 = fmaf(c2, w1, zc1);
      zd0 = fmaf(d2, w0, zd0); zd1 = fmaf(d2, w1, zd1);
    }
    float s0 = fmaxf(za0, 0.f) * u0 + fmaxf(za1, 0.f) * u1;
    float s1 = fmaxf(zb0, 0.f) * u0 + fmaxf(zb1, 0.f) * u1;
    float s2 = fmaxf(zc0, 0.f) * u0 + fmaxf(zc1, 0.f) * u1;
    float s3 = fmaxf(zd0, 0.f) * u0 + fmaxf(zd1, 0.f) * u1;
#pragma unroll
    for (int off = 32; off; off >>= 1) {
      s0 += __shfl_xor(s0, off, 64);
      s1 += __shfl_xor(s1, off, 64);
      s2 += __shfl_xor(s2, off, 64);
      s3 += __shfl_xor(s3, off, 64);
    }
    if (lane == 0) {
      float cc = cscal[g];
      out[row0] = s0 + cc;
      out[row0 + 1] = s1 + cc;
      out[row0 + 2] = s2 + cc;
      out[row0 + 3] = s3 + cc;
    }
  }
}

extern "C" void kernel_launch(void* const* d_in, const int* in_sizes, int n_in,
                              void* d_out, int out_size, void* d_ws, size_t ws_size,
                              hipStream_t stream) {
  const float* node_features = (const float*)d_in[0];
  const float* w_n2l        = (const float*)d_in[1];
  const float* bias_n2l     = (const float*)d_in[2];
  const float* bias_picked  = (const float*)d_in[3];
  const float* conv_W       = (const float*)d_in[4];
  const float* conv_b       = (const float*)d_in[5];
  const float* lin1_W       = (const float*)d_in[6];
  const float* lin1_b       = (const float*)d_in[7];
  const float* lout_W       = (const float*)d_in[8];
  const float* lout_b       = (const float*)d_in[9];
  const int*   edges_src    = (const int*)d_in[11];
  const int*   edges_dst    = (const int*)d_in[12];
  const int*   target_nodes = (const int*)d_in[13];
  const int*   picked_nodes = (const int*)d_in[14];
  float* q_out = (float*)d_out;

  // workspace layout
  float* base = (float*)d_ws;                          // N*D
  float* hA   = base + (size_t)Nn * Dd;                // B*N*D (level-1 out)
  float* hB   = hA + (size_t)Bg * Nn * Dd;             // B*N*D (level-2 out)
  int*   deg  = (int*)(hB + (size_t)Bg * Nn * Dd);     // B*N
  int*   offs = deg + (size_t)Bg * Nn;                 // B*N
  int*   ssrc = offs + (size_t)Bg * Nn;                // B*E
  float* gsum = (float*)(ssrc + (size_t)Bg * Eg);      // B*64
  float* cvec = gsum + Bg * Dd;                        // B*128
  float* uvec = cvec + Bg * Hh;                        // B*128
  float* csc  = uvec + Bg * Hh;                        // B

  hipMemsetAsync(deg, 0, (size_t)Bg * Nn * sizeof(int), stream);
  hipMemsetAsync(gsum, 0, (size_t)Bg * Dd * sizeof(float), stream);

  k_base<<<512, 256, 0, stream>>>(node_features, w_n2l, bias_n2l, base);
  k_hist<<<dim3(Eg / 256, Bg), 256, 0, stream>>>(edges_dst, deg);
  k_scan<<<Bg, 1024, 0, stream>>>(deg, offs);
  k_scatter<<<dim3(Eg / 256, Bg), 256, 0, stream>>>(edges_src, edges_dst, offs, ssrc);
  k_level<true><<<2048, 256, 0, stream>>>(base, hA, base, conv_W, conv_b,
                                          bias_picked, picked_nodes, deg, offs, ssrc);
  k_level<false><<<2048, 256, 0, stream>>>(hA, hB, base, conv_W, conv_b,
                                           bias_picked, picked_nodes, deg, offs, ssrc);
  k_gsum<<<dim3(32, Bg), 256, 0, stream>>>(hB, gsum);
  k_prep<<<Bg, 128, 0, stream>>>(hB, gsum, target_nodes, lin1_W, lin1_b, lout_W,
                                 lout_b, cvec, uvec, csc);
  k_final<<<2048, 256, 0, stream>>>(hB, lin1_W, cvec, uvec, csc, q_out);
}

// Round 4
// 763.415 us; speedup vs baseline: 1.3804x; 1.0758x over previous
//
#include <hip/hip_runtime.h>
#include <hip/hip_bf16.h>

#define Nn 20000
#define Bg 8
#define Eg 320000
#define FDim 128
#define Dd 64
#define Hh 128

__device__ __forceinline__ float bcastf(float v, int l) {
  return __int_as_float(__builtin_amdgcn_readlane(__float_as_int(v), l));
}

// K1: base = node_features @ w_n2l + bias_n2l   [N,128]@[128,64], grid-stride
__global__ __launch_bounds__(256) void k_base(const float* __restrict__ x,
                                              const float* __restrict__ W,
                                              const float* __restrict__ b,
                                              float* __restrict__ base) {
  __shared__ float Wl[FDim * Dd];   // 32 KB
  int t = threadIdx.x;
  for (int i = t; i < FDim * Dd; i += 256) Wl[i] = W[i];
  __syncthreads();
  int wv = t >> 6, lane = t & 63;
  float bias = b[lane];
  for (int row = blockIdx.x * 4 + wv; row < Nn; row += gridDim.x * 4) {
    float x0 = x[row * FDim + lane];
    float x1 = x[row * FDim + 64 + lane];
    float acc = bias;
#pragma unroll
    for (int k = 0; k < 64; ++k) acc = fmaf(bcastf(x0, k), Wl[k * Dd + lane], acc);
#pragma unroll
    for (int k = 0; k < 64; ++k) acc = fmaf(bcastf(x1, k), Wl[(64 + k) * Dd + lane], acc);
    base[row * Dd + lane] = acc;
  }
}

// K2: per-graph dst-degree histogram. XCD-affine: graph g = blockIdx.x & 7,
// so graph g's deg[] atomic lines live in one XCD's L2 only.
__global__ void k_hist(const int* __restrict__ dst, int* __restrict__ deg) {
  int g = blockIdx.x & 7;
  int c = blockIdx.x >> 3;
  int e = c * 256 + threadIdx.x;
  if (e < Eg) atomicAdd(&deg[g * Nn + dst[(size_t)g * Eg + e]], 1);
}

// K3: exclusive prefix-sum of deg -> offs (one block per graph)
__global__ __launch_bounds__(1024) void k_scan(const int* __restrict__ deg,
                                               int* __restrict__ offs) {
  int g = blockIdx.x;
  const int* dp = deg + g * Nn;
  int* op = offs + g * Nn;
  __shared__ int buf[1024];
  __shared__ int carry;
  if (threadIdx.x == 0) carry = 0;
  __syncthreads();
  for (int b0 = 0; b0 < Nn; b0 += 1024) {
    int idx = b0 + threadIdx.x;
    int v = (idx < Nn) ? dp[idx] : 0;
    buf[threadIdx.x] = v;
    __syncthreads();
    for (int off = 1; off < 1024; off <<= 1) {
      int tv = (threadIdx.x >= off) ? buf[threadIdx.x - off] : 0;
      __syncthreads();
      buf[threadIdx.x] += tv;
      __syncthreads();
    }
    int incl = buf[threadIdx.x];
    int cc = carry;
    if (idx < Nn) op[idx] = cc + incl - v;  // exclusive
    __syncthreads();
    if (threadIdx.x == 1023) carry = cc + incl;
    __syncthreads();
  }
}

// K4: counting-sort scatter of src only (offs becomes END pointer after this).
// XCD-affine: graph g = blockIdx.x & 7 -> ssrc/offs lines stay in one L2,
// random 4B writes merge there instead of 14x write-amplifying to HBM.
__global__ void k_scatter(const int* __restrict__ src, const int* __restrict__ dst,
                          int* __restrict__ offs, int* __restrict__ ssrc) {
  int g = blockIdx.x & 7;
  int c = blockIdx.x >> 3;
  int e = c * 256 + threadIdx.x;
  if (e < Eg) {
    size_t be = (size_t)g * Eg + e;
    int d = dst[be];
    int pos = atomicAdd(&offs[g * Nn + d], 1);
    ssrc[(size_t)g * Eg + pos] = src[be];
  }
}

// K5: fused SpMM (CSR gather, 8 outstanding loads) + conv matvec + relu.
// LV1: gather from shared `base` applying relu + picked-bias on the fly.
// XCD-affine: graph g = blockIdx.x & 7 -> h-gathers hit the local L2.
template <bool LV1>
__global__ __launch_bounds__(256) void k_level(
    const float* __restrict__ hin, float* __restrict__ hout,
    const float* __restrict__ base, const float* __restrict__ convW,
    const float* __restrict__ convb, const float* __restrict__ biasp,
    const int* __restrict__ picked, const int* __restrict__ deg,
    const int* __restrict__ offs, const int* __restrict__ ssrc) {
  __shared__ float Wl[Dd * Dd];  // 16 KB
  int t = threadIdx.x;
  for (int i = t; i < Dd * Dd; i += 256) Wl[i] = convW[i];
  __syncthreads();
  int wv = t >> 6, lane = t & 63;
  float cb = convb[lane];
  float bp = biasp[lane];
  int g = blockIdx.x & 7;
  int lb = blockIdx.x >> 3;              // 0..255 local block within graph
  int rstride = (gridDim.x >> 3) * 4;    // rows advanced per step
  int pick = picked[g];
  const int* sp = ssrc + (size_t)g * Eg;
  const float* sb = LV1 ? base : (hin + (size_t)g * Nn * Dd);
  float* outg = hout + (size_t)g * Nn * Dd;

  for (int i = lb * 4 + wv; i < Nn; i += rstride) {
    int end = offs[g * Nn + i];
    int dg = deg[g * Nn + i];
    int beg = end - dg;

    auto GATHER = [&](int s) -> float {
      float v = sb[(size_t)s * Dd + lane];
      if (LV1) {
        if (s == pick) v += bp;
        v = fmaxf(v, 0.f);
      }
      return v;
    };

    float acc = 0.f;
    if (dg <= 64) {
      int sv = 0;
      if (beg + lane < end) sv = sp[beg + lane];  // one coalesced index load
      int j = 0;
      for (; j + 8 <= dg; j += 8) {
        int s0 = __builtin_amdgcn_readlane(sv, j + 0);
        int s1 = __builtin_amdgcn_readlane(sv, j + 1);
        int s2 = __builtin_amdgcn_readlane(sv, j + 2);
        int s3 = __builtin_amdgcn_readlane(sv, j + 3);
        int s4 = __builtin_amdgcn_readlane(sv, j + 4);
        int s5 = __builtin_amdgcn_readlane(sv, j + 5);
        int s6 = __builtin_amdgcn_readlane(sv, j + 6);
        int s7 = __builtin_amdgcn_readlane(sv, j + 7);
        float v0 = GATHER(s0), v1 = GATHER(s1), v2 = GATHER(s2), v3 = GATHER(s3);
        float v4 = GATHER(s4), v5 = GATHER(s5), v6 = GATHER(s6), v7 = GATHER(s7);
        acc += (((v0 + v1) + (v2 + v3)) + ((v4 + v5) + (v6 + v7)));
      }
      for (; j < dg; ++j) acc += GATHER(__builtin_amdgcn_readlane(sv, j));
    } else {  // degree > 64 fallback (statistically never at avg deg 16)
      for (int e = beg; e < end; ++e) acc += GATHER(sp[e]);
    }
    float wsc = dg ? 1.0f / (float)dg : 0.f;
    acc *= wsc;

    float out = base[(size_t)i * Dd + lane] + cb;
    if (i == pick) out += bp;
#pragma unroll
    for (int d = 0; d < Dd; ++d) out = fmaf(bcastf(acc, d), Wl[d * Dd + lane], out);
    out = fmaxf(out, 0.f);
    outg[(size_t)i * Dd + lane] = out;
  }
}

// K6: per-graph column sums of h (for graph mean), XCD-affine
__global__ void k_gsum(const float* __restrict__ h, float* __restrict__ gsum) {
  int g = blockIdx.x & 7;
  int lb = blockIdx.x >> 3;  // 0..31
  int wv = threadIdx.x >> 6, lane = threadIdx.x & 63;
  __shared__ float red[4][Dd];
  float acc = 0.f;
  const float* hg = h + (size_t)g * Nn * Dd;
  int rstride = (gridDim.x >> 3) * 4;
  for (int r = lb * 4 + wv; r < Nn; r += rstride)
    acc += hg[(size_t)r * Dd + lane];
  red[wv][lane] = acc;
  __syncthreads();
  if (wv == 0) {
    float s = red[0][lane] + red[1][lane] + red[2][lane] + red[3][lane];
    atomicAdd(&gsum[g * Dd + lane], s);
  }
}

// K7: per-graph constants: cvec = g_embed@lin1_W[64:] + lin1_b ; u = lout_W@t ; c = lout_b.t
__global__ __launch_bounds__(128) void k_prep(
    const float* __restrict__ h, const float* __restrict__ gsum,
    const int* __restrict__ tgt, const float* __restrict__ lin1W,
    const float* __restrict__ lin1b, const float* __restrict__ loutW,
    const float* __restrict__ loutb, float* __restrict__ cvec,
    float* __restrict__ uvec, float* __restrict__ cscal) {
  int g = blockIdx.x;
  int k = threadIdx.x;
  __shared__ float tv[Dd], ge[Dd];
  if (k < Dd) {
    tv[k] = h[(size_t)g * Nn * Dd + (size_t)tgt[g] * Dd + k];
    ge[k] = gsum[g * Dd + k] * (1.0f / Nn);
  }
  __syncthreads();
  float cv = lin1b[k];
#pragma unroll 8
  for (int d = 0; d < Dd; ++d) cv = fmaf(ge[d], lin1W[(Dd + d) * Hh + k], cv);
  cvec[g * Hh + k] = cv;
  float uu = 0.f;
#pragma unroll 8
  for (int j = 0; j < Dd; ++j) uu = fmaf(loutW[k * Dd + j], tv[j], uu);
  uvec[g * Hh + k] = uu;
  if (k == 0) {
    float c = 0.f;
    for (int j = 0; j < Dd; ++j) c += loutb[j] * tv[j];
    cscal[g] = c;
  }
}

// K8: q[g,i] = sum_k relu(h_i . W1[:,k] + cvec[k]) * u[k] + c   (4 rows per wave)
__global__ __launch_bounds__(256) void k_final(
    const float* __restrict__ h, const float* __restrict__ lin1W,
    const float* __restrict__ cvec, const float* __restrict__ uvec,
    const float* __restrict__ cscal, float* __restrict__ out) {
  __shared__ float Wl[Dd * Hh];  // 32 KB: lin1_W rows 0..63
  int t = threadIdx.x;
  for (int i = t; i < Dd * Hh; i += 256) Wl[i] = lin1W[i];
  __syncthreads();
  int wv = t >> 6, lane = t & 63;
  int tot = Bg * Nn / 4;  // quads never straddle a graph (N % 4 == 0)
  for (int p = blockIdx.x * 4 + wv; p < tot; p += gridDim.x * 4) {
    int row0 = p * 4;
    int g = row0 / Nn;
    int i0 = row0 - g * Nn;
    const float* hr = h + (size_t)g * Nn * Dd + (size_t)i0 * Dd;
    float ha = hr[lane], hb = hr[64 + lane], hc = hr[128 + lane], hd = hr[192 + lane];
    float c0 = cvec[g * Hh + lane], c1 = cvec[g * Hh + 64 + lane];
    float u0 = uvec[g * Hh + lane], u1 = uvec[g * Hh + 64 + lane];
    float za0 = c0, za1 = c1, zb0 = c0, zb1 = c1;
    float zc0 = c0, zc1 = c1, zd0 = c0, zd1 = c1;
#pragma unroll
    for (int d = 0; d < Dd; ++d) {
      float w0 = Wl[d * Hh + lane], w1 = Wl[d * Hh + 64 + lane];
      float a = bcastf(ha, d), b2 = bcastf(hb, d);
      float c2 = bcastf(hc, d), d2 = bcastf(hd, d);
      za0 = fmaf(a, w0, za0);  za1 = fmaf(a, w1, za1);
      zb0 = fmaf(b2, w0, zb0); zb1 = fmaf(b2, w1, zb1);
      zc0 = fmaf(c2, w0, zc0); zc1 = fmaf(c2, w1, zc1);
      zd0 = fmaf(d2, w0, zd0); zd1 = fmaf(d2, w1, zd1);
    }
    float s0 = fmaxf(za0, 0.f) * u0 + fmaxf(za1, 0.f) * u1;
    float s1 = fmaxf(zb0, 0.f) * u0 + fmaxf(zb1, 0.f) * u1;
    float s2 = fmaxf(zc0, 0.f) * u0 + fmaxf(zc1, 0.f) * u1;
    float s3 = fmaxf(zd0, 0.f) * u0 + fmaxf(zd1, 0.f) * u1;
#pragma unroll
    for (int off = 32; off; off >>= 1) {
      s0 += __shfl_xor(s0, off, 64);
      s1 += __shfl_xor(s1, off, 64);
      s2 += __shfl_xor(s2, off, 64);
      s3 += __shfl_xor(s3, off, 64);
    }
    if (lane == 0) {
      float cc = cscal[g];
      out[row0] = s0 + cc;
      out[row0 + 1] = s1 + cc;
      out[row0 + 2] = s2 + cc;
      out[row0 + 3] = s3 + cc;
    }
  }
}

extern "C" void kernel_launch(void* const* d_in, const int* in_sizes, int n_in,
                              void* d_out, int out_size, void* d_ws, size_t ws_size,
                              hipStream_t stream) {
  const float* node_features = (const float*)d_in[0];
  const float* w_n2l        = (const float*)d_in[1];
  const float* bias_n2l     = (const float*)d_in[2];
  const float* bias_picked  = (const float*)d_in[3];
  const float* conv_W       = (const float*)d_in[4];
  const float* conv_b       = (const float*)d_in[5];
  const float* lin1_W       = (const float*)d_in[6];
  const float* lin1_b       = (const float*)d_in[7];
  const float* lout_W       = (const float*)d_in[8];
  const float* lout_b       = (const float*)d_in[9];
  const int*   edges_src    = (const int*)d_in[11];
  const int*   edges_dst    = (const int*)d_in[12];
  const int*   target_nodes = (const int*)d_in[13];
  const int*   picked_nodes = (const int*)d_in[14];
  float* q_out = (float*)d_out;

  // workspace layout
  float* base = (float*)d_ws;                          // N*D
  float* hA   = base + (size_t)Nn * Dd;                // B*N*D (level-1 out)
  float* hB   = hA + (size_t)Bg * Nn * Dd;             // B*N*D (level-2 out)
  int*   deg  = (int*)(hB + (size_t)Bg * Nn * Dd);     // B*N
  int*   offs = deg + (size_t)Bg * Nn;                 // B*N
  int*   ssrc = offs + (size_t)Bg * Nn;                // B*E
  float* gsum = (float*)(ssrc + (size_t)Bg * Eg);      // B*64
  float* cvec = gsum + Bg * Dd;                        // B*128
  float* uvec = cvec + Bg * Hh;                        // B*128
  float* csc  = uvec + Bg * Hh;                        // B

  hipMemsetAsync(deg, 0, (size_t)Bg * Nn * sizeof(int), stream);
  hipMemsetAsync(gsum, 0, (size_t)Bg * Dd * sizeof(float), stream);

  k_base<<<512, 256, 0, stream>>>(node_features, w_n2l, bias_n2l, base);
  k_hist<<<(Eg / 256) * Bg, 256, 0, stream>>>(edges_dst, deg);
  k_scan<<<Bg, 1024, 0, stream>>>(deg, offs);
  k_scatter<<<(Eg / 256) * Bg, 256, 0, stream>>>(edges_src, edges_dst, offs, ssrc);
  k_level<true><<<2048, 256, 0, stream>>>(base, hA, base, conv_W, conv_b,
                                          bias_picked, picked_nodes, deg, offs, ssrc);
  k_level<false><<<2048, 256, 0, stream>>>(hA, hB, base, conv_W, conv_b,
                                           bias_picked, picked_nodes, deg, offs, ssrc);
  k_gsum<<<256, 256, 0, stream>>>(hB, gsum);
  k_prep<<<Bg, 128, 0, stream>>>(hB, gsum, target_nodes, lin1_W, lin1_b, lout_W,
                                 lout_b, cvec, uvec, csc);
  k_final<<<2048, 256, 0, stream>>>(hB, lin1_W, cvec, uvec, csc, q_out);
}

// Round 5
// 730.797 us; speedup vs baseline: 1.4420x; 1.0446x over previous
//
#include <hip/hip_runtime.h>
#include <hip/hip_bf16.h>
#include <hip/hip_fp16.h>

#define Nn 20000
#define Bg 8
#define Eg 320000
#define FDim 128
#define Dd 64
#define Hh 128

__device__ __forceinline__ float bcastf(float v, int l) {
  return __int_as_float(__builtin_amdgcn_readlane(__float_as_int(v), l));
}

// K1: base = node_features @ w_n2l + bias_n2l   [N,128]@[128,64], grid-stride
__global__ __launch_bounds__(256) void k_base(const float* __restrict__ x,
                                              const float* __restrict__ W,
                                              const float* __restrict__ b,
                                              float* __restrict__ base) {
  __shared__ float Wl[FDim * Dd];   // 32 KB
  int t = threadIdx.x;
  for (int i = t; i < FDim * Dd; i += 256) Wl[i] = W[i];
  __syncthreads();
  int wv = t >> 6, lane = t & 63;
  float bias = b[lane];
  for (int row = blockIdx.x * 4 + wv; row < Nn; row += gridDim.x * 4) {
    float x0 = x[row * FDim + lane];
    float x1 = x[row * FDim + 64 + lane];
    float acc = bias;
#pragma unroll
    for (int k = 0; k < 64; ++k) acc = fmaf(bcastf(x0, k), Wl[k * Dd + lane], acc);
#pragma unroll
    for (int k = 0; k < 64; ++k) acc = fmaf(bcastf(x1, k), Wl[(64 + k) * Dd + lane], acc);
    base[row * Dd + lane] = acc;
  }
}

// K2: per-graph dst-degree histogram. XCD-affine: graph g = blockIdx.x & 7.
__global__ void k_hist(const int* __restrict__ dst, int* __restrict__ deg) {
  int g = blockIdx.x & 7;
  int c = blockIdx.x >> 3;
  int e = c * 256 + threadIdx.x;
  if (e < Eg) atomicAdd(&deg[g * Nn + dst[(size_t)g * Eg + e]], 1);
}

// K3: exclusive prefix-sum of deg -> offs. int4: 4 elems/thread, 5 chunks of 4096.
__global__ __launch_bounds__(1024) void k_scan(const int* __restrict__ deg,
                                               int* __restrict__ offs) {
  int g = blockIdx.x;
  const int* dp = deg + g * Nn;
  int* op = offs + g * Nn;
  __shared__ int buf[1024];
  __shared__ int carry;
  if (threadIdx.x == 0) carry = 0;
  __syncthreads();
  for (int b0 = 0; b0 < Nn; b0 += 4096) {
    int gidx = b0 + threadIdx.x * 4;
    int4 v = make_int4(0, 0, 0, 0);
    bool ok = (gidx + 3 < Nn);
    if (ok) v = *(const int4*)(dp + gidx);
    int s0 = v.x, s1 = s0 + v.y, s2 = s1 + v.z, s3 = s2 + v.w;
    buf[threadIdx.x] = s3;
    __syncthreads();
    for (int off = 1; off < 1024; off <<= 1) {
      int tv = (threadIdx.x >= off) ? buf[threadIdx.x - off] : 0;
      __syncthreads();
      buf[threadIdx.x] += tv;
      __syncthreads();
    }
    int excl = buf[threadIdx.x] - s3;
    int cc = carry;
    if (ok) {
      int4 o;
      o.x = cc + excl;
      o.y = cc + excl + s0;
      o.z = cc + excl + s1;
      o.w = cc + excl + s2;
      *(int4*)(op + gidx) = o;
    }
    __syncthreads();
    if (threadIdx.x == 1023) carry = cc + buf[1023];
    __syncthreads();
  }
}

// K4: counting-sort scatter of src (offs becomes END pointer). XCD-affine.
__global__ void k_scatter(const int* __restrict__ src, const int* __restrict__ dst,
                          int* __restrict__ offs, int* __restrict__ ssrc) {
  int g = blockIdx.x & 7;
  int c = blockIdx.x >> 3;
  int e = c * 256 + threadIdx.x;
  if (e < Eg) {
    size_t be = (size_t)g * Eg + e;
    int d = dst[be];
    int pos = atomicAdd(&offs[g * Nn + d], 1);
    ssrc[(size_t)g * Eg + pos] = src[be];
  }
}

// K5: h0[g] = fp16(relu(base + onehot(picked)*bias_picked)). XCD-affine.
// fp16 shrinks the gather working set to 2.56 MB/graph -> L2-resident.
__global__ void k_init16(const float* __restrict__ base, const float* __restrict__ biasp,
                         const int* __restrict__ picked, __half* __restrict__ h0) {
  int g = blockIdx.x & 7;
  int lb = blockIdx.x >> 3;
  int pick = picked[g];
  int nth = (gridDim.x >> 3) * 256;
  __half* out = h0 + (size_t)g * Nn * Dd;
  int tot = Nn * Dd / 4;
  for (int q = lb * 256 + threadIdx.x; q < tot; q += nth) {
    int i = q >> 4;
    float4 v = *(const float4*)&base[q * 4];
    if (i == pick) {
      int c0 = (q & 15) * 4;
      v.x += biasp[c0]; v.y += biasp[c0 + 1]; v.z += biasp[c0 + 2]; v.w += biasp[c0 + 3];
    }
    __half2 a = __floats2half2_rn(fmaxf(v.x, 0.f), fmaxf(v.y, 0.f));
    __half2 b = __floats2half2_rn(fmaxf(v.z, 0.f), fmaxf(v.w, 0.f));
    *(__half2*)(out + (size_t)q * 4) = a;
    *(__half2*)(out + (size_t)q * 4 + 2) = b;
  }
}

// K6: fused SpMM (fp16 gather, 8 outstanding) + conv matvec + relu. XCD-affine.
// OUT16: store fp16 (level-1 output, consumed only by level-2 gathers);
// else store fp32 (level-2 output, consumed by gsum/prep/final).
template <bool OUT16>
__global__ __launch_bounds__(256) void k_level(
    const __half* __restrict__ hin, float* __restrict__ hout32,
    __half* __restrict__ hout16, const float* __restrict__ base,
    const float* __restrict__ convW, const float* __restrict__ convb,
    const float* __restrict__ biasp, const int* __restrict__ picked,
    const int* __restrict__ deg, const int* __restrict__ offs,
    const int* __restrict__ ssrc) {
  __shared__ float Wl[Dd * Dd];  // 16 KB
  int t = threadIdx.x;
  for (int i = t; i < Dd * Dd; i += 256) Wl[i] = convW[i];
  __syncthreads();
  int wv = t >> 6, lane = t & 63;
  float cb = convb[lane];
  float bp = biasp[lane];
  int g = blockIdx.x & 7;
  int lb = blockIdx.x >> 3;
  int rstride = (gridDim.x >> 3) * 4;
  int pick = picked[g];
  const int* sp = ssrc + (size_t)g * Eg;
  const __half* hg = hin + (size_t)g * Nn * Dd;

  for (int i = lb * 4 + wv; i < Nn; i += rstride) {
    int end = offs[g * Nn + i];
    int dg = deg[g * Nn + i];
    int beg = end - dg;

    float acc = 0.f;
    if (dg <= 64) {
      int sv = 0;
      if (beg + lane < end) sv = sp[beg + lane];  // one coalesced index load
      int j = 0;
      for (; j + 8 <= dg; j += 8) {
        int s0 = __builtin_amdgcn_readlane(sv, j + 0);
        int s1 = __builtin_amdgcn_readlane(sv, j + 1);
        int s2 = __builtin_amdgcn_readlane(sv, j + 2);
        int s3 = __builtin_amdgcn_readlane(sv, j + 3);
        int s4 = __builtin_amdgcn_readlane(sv, j + 4);
        int s5 = __builtin_amdgcn_readlane(sv, j + 5);
        int s6 = __builtin_amdgcn_readlane(sv, j + 6);
        int s7 = __builtin_amdgcn_readlane(sv, j + 7);
        float v0 = __half2float(hg[(size_t)s0 * Dd + lane]);
        float v1 = __half2float(hg[(size_t)s1 * Dd + lane]);
        float v2 = __half2float(hg[(size_t)s2 * Dd + lane]);
        float v3 = __half2float(hg[(size_t)s3 * Dd + lane]);
        float v4 = __half2float(hg[(size_t)s4 * Dd + lane]);
        float v5 = __half2float(hg[(size_t)s5 * Dd + lane]);
        float v6 = __half2float(hg[(size_t)s6 * Dd + lane]);
        float v7 = __half2float(hg[(size_t)s7 * Dd + lane]);
        acc += (((v0 + v1) + (v2 + v3)) + ((v4 + v5) + (v6 + v7)));
      }
      for (; j < dg; ++j)
        acc += __half2float(hg[(size_t)__builtin_amdgcn_readlane(sv, j) * Dd + lane]);
    } else {  // degree > 64 fallback
      for (int e = beg; e < end; ++e)
        acc += __half2float(hg[(size_t)sp[e] * Dd + lane]);
    }
    float wsc = dg ? 1.0f / (float)dg : 0.f;
    acc *= wsc;

    float out = base[(size_t)i * Dd + lane] + cb;
    if (i == pick) out += bp;
#pragma unroll
    for (int d = 0; d < Dd; ++d) out = fmaf(bcastf(acc, d), Wl[d * Dd + lane], out);
    out = fmaxf(out, 0.f);
    if (OUT16)
      hout16[(size_t)g * Nn * Dd + (size_t)i * Dd + lane] = __float2half(out);
    else
      hout32[(size_t)g * Nn * Dd + (size_t)i * Dd + lane] = out;
  }
}

// K7: per-graph column sums of h (for graph mean), XCD-affine, fp32 h
__global__ void k_gsum(const float* __restrict__ h, float* __restrict__ gsum) {
  int g = blockIdx.x & 7;
  int lb = blockIdx.x >> 3;
  int wv = threadIdx.x >> 6, lane = threadIdx.x & 63;
  __shared__ float red[4][Dd];
  float acc = 0.f;
  const float* hg = h + (size_t)g * Nn * Dd;
  int rstride = (gridDim.x >> 3) * 4;
  for (int r = lb * 4 + wv; r < Nn; r += rstride)
    acc += hg[(size_t)r * Dd + lane];
  red[wv][lane] = acc;
  __syncthreads();
  if (wv == 0) {
    float s = red[0][lane] + red[1][lane] + red[2][lane] + red[3][lane];
    atomicAdd(&gsum[g * Dd + lane], s);
  }
}

// K8: per-graph constants
__global__ __launch_bounds__(128) void k_prep(
    const float* __restrict__ h, const float* __restrict__ gsum,
    const int* __restrict__ tgt, const float* __restrict__ lin1W,
    const float* __restrict__ lin1b, const float* __restrict__ loutW,
    const float* __restrict__ loutb, float* __restrict__ cvec,
    float* __restrict__ uvec, float* __restrict__ cscal) {
  int g = blockIdx.x;
  int k = threadIdx.x;
  __shared__ float tv[Dd], ge[Dd];
  if (k < Dd) {
    tv[k] = h[(size_t)g * Nn * Dd + (size_t)tgt[g] * Dd + k];
    ge[k] = gsum[g * Dd + k] * (1.0f / Nn);
  }
  __syncthreads();
  float cv = lin1b[k];
#pragma unroll 8
  for (int d = 0; d < Dd; ++d) cv = fmaf(ge[d], lin1W[(Dd + d) * Hh + k], cv);
  cvec[g * Hh + k] = cv;
  float uu = 0.f;
#pragma unroll 8
  for (int j = 0; j < Dd; ++j) uu = fmaf(loutW[k * Dd + j], tv[j], uu);
  uvec[g * Hh + k] = uu;
  if (k == 0) {
    float c = 0.f;
    for (int j = 0; j < Dd; ++j) c += loutb[j] * tv[j];
    cscal[g] = c;
  }
}

// K9: q[g,i] = sum_k relu(h_i . W1[:,k] + cvec[k]) * u[k] + c   (4 rows per wave)
__global__ __launch_bounds__(256) void k_final(
    const float* __restrict__ h, const float* __restrict__ lin1W,
    const float* __restrict__ cvec, const float* __restrict__ uvec,
    const float* __restrict__ cscal, float* __restrict__ out) {
  __shared__ float Wl[Dd * Hh];  // 32 KB: lin1_W rows 0..63
  int t = threadIdx.x;
  for (int i = t; i < Dd * Hh; i += 256) Wl[i] = lin1W[i];
  __syncthreads();
  int wv = t >> 6, lane = t & 63;
  int tot = Bg * Nn / 4;
  for (int p = blockIdx.x * 4 + wv; p < tot; p += gridDim.x * 4) {
    int row0 = p * 4;
    int g = row0 / Nn;
    int i0 = row0 - g * Nn;
    const float* hr = h + (size_t)g * Nn * Dd + (size_t)i0 * Dd;
    float ha = hr[lane], hb = hr[64 + lane], hc = hr[128 + lane], hd = hr[192 + lane];
    float c0 = cvec[g * Hh + lane], c1 = cvec[g * Hh + 64 + lane];
    float u0 = uvec[g * Hh + lane], u1 = uvec[g * Hh + 64 + lane];
    float za0 = c0, za1 = c1, zb0 = c0, zb1 = c1;
    float zc0 = c0, zc1 = c1, zd0 = c0, zd1 = c1;
#pragma unroll
    for (int d = 0; d < Dd; ++d) {
      float w0 = Wl[d * Hh + lane], w1 = Wl[d * Hh + 64 + lane];
      float a = bcastf(ha, d), b2 = bcastf(hb, d);
      float c2 = bcastf(hc, d), d2 = bcastf(hd, d);
      za0 = fmaf(a, w0, za0);  za1 = fmaf(a, w1, za1);
      zb0 = fmaf(b2, w0, zb0); zb1 = fmaf(b2, w1, zb1);
      zc0 = fmaf(c2, w0, zc0); zc1 = fmaf(c2, w1, zc1);
      zd0 = fmaf(d2, w0, zd0); zd1 = fmaf(d2, w1, zd1);
    }
    float s0 = fmaxf(za0, 0.f) * u0 + fmaxf(za1, 0.f) * u1;
    float s1 = fmaxf(zb0, 0.f) * u0 + fmaxf(zb1, 0.f) * u1;
    float s2 = fmaxf(zc0, 0.f) * u0 + fmaxf(zc1, 0.f) * u1;
    float s3 = fmaxf(zd0, 0.f) * u0 + fmaxf(zd1, 0.f) * u1;
#pragma unroll
    for (int off = 32; off; off >>= 1) {
      s0 += __shfl_xor(s0, off, 64);
      s1 += __shfl_xor(s1, off, 64);
      s2 += __shfl_xor(s2, off, 64);
      s3 += __shfl_xor(s3, off, 64);
    }
    if (lane == 0) {
      float cc = cscal[g];
      out[row0] = s0 + cc;
      out[row0 + 1] = s1 + cc;
      out[row0 + 2] = s2 + cc;
      out[row0 + 3] = s3 + cc;
    }
  }
}

extern "C" void kernel_launch(void* const* d_in, const int* in_sizes, int n_in,
                              void* d_out, int out_size, void* d_ws, size_t ws_size,
                              hipStream_t stream) {
  const float* node_features = (const float*)d_in[0];
  const float* w_n2l        = (const float*)d_in[1];
  const float* bias_n2l     = (const float*)d_in[2];
  const float* bias_picked  = (const float*)d_in[3];
  const float* conv_W       = (const float*)d_in[4];
  const float* conv_b       = (const float*)d_in[5];
  const float* lin1_W       = (const float*)d_in[6];
  const float* lin1_b       = (const float*)d_in[7];
  const float* lout_W       = (const float*)d_in[8];
  const float* lout_b       = (const float*)d_in[9];
  const int*   edges_src    = (const int*)d_in[11];
  const int*   edges_dst    = (const int*)d_in[12];
  const int*   target_nodes = (const int*)d_in[13];
  const int*   picked_nodes = (const int*)d_in[14];
  float* q_out = (float*)d_out;

  // workspace layout
  float*  base = (float*)d_ws;                           // N*D fp32
  __half* h0h  = (__half*)(base + (size_t)Nn * Dd);      // B*N*D fp16
  __half* hAh  = h0h + (size_t)Bg * Nn * Dd;             // B*N*D fp16
  float*  hB   = (float*)(hAh + (size_t)Bg * Nn * Dd);   // B*N*D fp32
  int*    deg  = (int*)(hB + (size_t)Bg * Nn * Dd);      // B*N
  int*    offs = deg + (size_t)Bg * Nn;                  // B*N
  int*    ssrc = offs + (size_t)Bg * Nn;                 // B*E
  float*  gsum = (float*)(ssrc + (size_t)Bg * Eg);       // B*64
  float*  cvec = gsum + Bg * Dd;                         // B*128
  float*  uvec = cvec + Bg * Hh;                         // B*128
  float*  csc  = uvec + Bg * Hh;                         // B

  hipMemsetAsync(deg, 0, (size_t)Bg * Nn * sizeof(int), stream);
  hipMemsetAsync(gsum, 0, (size_t)Bg * Dd * sizeof(float), stream);

  k_base<<<512, 256, 0, stream>>>(node_features, w_n2l, bias_n2l, base);
  k_hist<<<(Eg / 256) * Bg, 256, 0, stream>>>(edges_dst, deg);
  k_scan<<<Bg, 1024, 0, stream>>>(deg, offs);
  k_scatter<<<(Eg / 256) * Bg, 256, 0, stream>>>(edges_src, edges_dst, offs, ssrc);
  k_init16<<<512, 256, 0, stream>>>(base, bias_picked, picked_nodes, h0h);
  k_level<true><<<2048, 256, 0, stream>>>(h0h, hB, hAh, base, conv_W, conv_b,
                                          bias_picked, picked_nodes, deg, offs, ssrc);
  k_level<false><<<2048, 256, 0, stream>>>(hAh, hB, hAh, base, conv_W, conv_b,
                                           bias_picked, picked_nodes, deg, offs, ssrc);
  k_gsum<<<256, 256, 0, stream>>>(hB, gsum);
  k_prep<<<Bg, 128, 0, stream>>>(hB, gsum, target_nodes, lin1_W, lin1_b, lout_W,
                                 lout_b, cvec, uvec, csc);
  k_final<<<2048, 256, 0, stream>>>(hB, lin1_W, cvec, uvec, csc, q_out);
}

// Round 6
// 636.314 us; speedup vs baseline: 1.6561x; 1.1485x over previous
//
#include <hip/hip_runtime.h>
#include <hip/hip_bf16.h>
#include <hip/hip_fp16.h>

#define Nn 20000
#define Bg 8
#define Eg 320000
#define FDim 128
#define Dd 64
#define Hh 128

__device__ __forceinline__ float bcastf(float v, int l) {
  return __int_as_float(__builtin_amdgcn_readlane(__float_as_int(v), l));
}

// K1: base = x @ w_n2l + bias ; also b16 = fp16(relu(base)) (shared gather source)
__global__ __launch_bounds__(256) void k_base(const float* __restrict__ x,
                                              const float* __restrict__ W,
                                              const float* __restrict__ b,
                                              float* __restrict__ base,
                                              __half* __restrict__ b16) {
  __shared__ float Wl[FDim * Dd];   // 32 KB
  int t = threadIdx.x;
  for (int i = t; i < FDim * Dd; i += 256) Wl[i] = W[i];
  __syncthreads();
  int wv = t >> 6, lane = t & 63;
  float bias = b[lane];
  for (int row = blockIdx.x * 4 + wv; row < Nn; row += gridDim.x * 4) {
    float x0 = x[row * FDim + lane];
    float x1 = x[row * FDim + 64 + lane];
    float acc = bias;
#pragma unroll
    for (int k = 0; k < 64; ++k) acc = fmaf(bcastf(x0, k), Wl[k * Dd + lane], acc);
#pragma unroll
    for (int k = 0; k < 64; ++k) acc = fmaf(bcastf(x1, k), Wl[(64 + k) * Dd + lane], acc);
    base[row * Dd + lane] = acc;
    b16[row * Dd + lane] = __float2half(fmaxf(acc, 0.f));
  }
}

// K2: per-graph dst-degree histogram, int4 (4 edges/thread), XCD-affine.
__global__ void k_hist(const int* __restrict__ dst, int* __restrict__ deg) {
  int g = blockIdx.x & 7;
  int c = blockIdx.x >> 3;
  int e4 = (c * 256 + threadIdx.x) * 4;
  if (e4 < Eg) {
    int4 d4 = *(const int4*)(dst + (size_t)g * Eg + e4);
    int* dp = deg + g * Nn;
    atomicAdd(&dp[d4.x], 1);
    atomicAdd(&dp[d4.y], 1);
    atomicAdd(&dp[d4.z], 1);
    atomicAdd(&dp[d4.w], 1);
  }
}

// K3: exclusive prefix-sum of deg -> offs. int4: 4 elems/thread.
__global__ __launch_bounds__(1024) void k_scan(const int* __restrict__ deg,
                                               int* __restrict__ offs) {
  int g = blockIdx.x;
  const int* dp = deg + g * Nn;
  int* op = offs + g * Nn;
  __shared__ int buf[1024];
  __shared__ int carry;
  if (threadIdx.x == 0) carry = 0;
  __syncthreads();
  for (int b0 = 0; b0 < Nn; b0 += 4096) {
    int gidx = b0 + threadIdx.x * 4;
    int4 v = make_int4(0, 0, 0, 0);
    bool ok = (gidx + 3 < Nn);
    if (ok) v = *(const int4*)(dp + gidx);
    int s0 = v.x, s1 = s0 + v.y, s2 = s1 + v.z, s3 = s2 + v.w;
    buf[threadIdx.x] = s3;
    __syncthreads();
    for (int off = 1; off < 1024; off <<= 1) {
      int tv = (threadIdx.x >= off) ? buf[threadIdx.x - off] : 0;
      __syncthreads();
      buf[threadIdx.x] += tv;
      __syncthreads();
    }
    int excl = buf[threadIdx.x] - s3;
    int cc = carry;
    if (ok) {
      int4 o;
      o.x = cc + excl;
      o.y = cc + excl + s0;
      o.z = cc + excl + s1;
      o.w = cc + excl + s2;
      *(int4*)(op + gidx) = o;
    }
    __syncthreads();
    if (threadIdx.x == 1023) carry = cc + buf[1023];
    __syncthreads();
  }
}

// K4: counting-sort scatter, int4 reads (offs becomes END pointer). XCD-affine.
__global__ void k_scatter(const int* __restrict__ src, const int* __restrict__ dst,
                          int* __restrict__ offs, int* __restrict__ ssrc) {
  int g = blockIdx.x & 7;
  int c = blockIdx.x >> 3;
  int e4 = (c * 256 + threadIdx.x) * 4;
  if (e4 < Eg) {
    size_t be = (size_t)g * Eg + e4;
    int4 d4 = *(const int4*)(dst + be);
    int4 s4 = *(const int4*)(src + be);
    int* op = offs + g * Nn;
    int* sp = ssrc + (size_t)g * Eg;
    sp[atomicAdd(&op[d4.x], 1)] = s4.x;
    sp[atomicAdd(&op[d4.y], 1)] = s4.y;
    sp[atomicAdd(&op[d4.z], 1)] = s4.z;
    sp[atomicAdd(&op[d4.w], 1)] = s4.w;
  }
}

// K5: fused SpMM + conv matvec + relu. Wave handles a row PAIR (CSR-adjacent,
// so one coalesced index load covers both edge lists). conv_W column in VGPRs.
// LV1: gathers shared b16=fp16(relu(base)); picked-node handled analytically
//      via per-row count of src==pick times delta[lane].
// !LV1: gathers per-graph fp16 hA; writes fp32 hB and accumulates gsum.
template <bool LV1>
__global__ __launch_bounds__(256) void k_level(
    const __half* __restrict__ hin, float* __restrict__ hout32,
    __half* __restrict__ hout16, const float* __restrict__ base,
    const float* __restrict__ convW, const float* __restrict__ convb,
    const float* __restrict__ biasp, const int* __restrict__ picked,
    const int* __restrict__ deg, const int* __restrict__ offs,
    const int* __restrict__ ssrc, float* __restrict__ gsum) {
  int t = threadIdx.x;
  int wv = t >> 6, lane = t & 63;
  float wcol[Dd];  // conv_W column `lane` in registers
#pragma unroll
  for (int d = 0; d < Dd; ++d) wcol[d] = convW[d * Dd + lane];
  float cb = convb[lane];
  float bp = biasp[lane];
  int g = blockIdx.x & 7;
  int lb = blockIdx.x >> 3;
  int pstride = (gridDim.x >> 3) * 4;
  int pick = picked[g];
  int gN = g * Nn;
  const int* sp = ssrc + (size_t)g * Eg;
  const __half* hg = LV1 ? hout16 /*unused*/ : hin;  // set below
  const __half* src16 = LV1 ? hin : (hin + (size_t)g * Nn * Dd);
  float delta = 0.f;
  if (LV1) {
    float db = base[(size_t)pick * Dd + lane];
    float d16 = __half2float(__float2half(fmaxf(db, 0.f)));
    delta = fmaxf(db + bp, 0.f) - d16;
  }
  float gs = 0.f;

  auto GH = [&](int s) -> float {
    return __half2float(src16[((unsigned)s << 6) + lane]);
  };

  for (int p = lb * 4 + wv; p < Nn / 2; p += pstride) {
    int i0 = p * 2, i1 = i0 + 1;
    int2 dg2 = *(const int2*)&deg[gN + i0];
    int2 of2 = *(const int2*)&offs[gN + i0];
    int d0 = dg2.x, d1 = dg2.y;
    int beg0 = of2.x - d0;
    int dtot = d0 + d1;

    float a0 = 0.f, a1 = 0.f;
    int c0 = 0, c1 = 0;
    if (dtot <= 64) {
      int svm = 0;
      if (lane < dtot) svm = sp[beg0 + lane];  // one coalesced index load, both rows
      int cch = 0;
      auto CHUNK8 = [&](int j) -> float {
        int s0 = __builtin_amdgcn_readlane(svm, j + 0);
        int s1 = __builtin_amdgcn_readlane(svm, j + 1);
        int s2 = __builtin_amdgcn_readlane(svm, j + 2);
        int s3 = __builtin_amdgcn_readlane(svm, j + 3);
        int s4 = __builtin_amdgcn_readlane(svm, j + 4);
        int s5 = __builtin_amdgcn_readlane(svm, j + 5);
        int s6 = __builtin_amdgcn_readlane(svm, j + 6);
        int s7 = __builtin_amdgcn_readlane(svm, j + 7);
        if (LV1)
          cch = (s0 == pick) + (s1 == pick) + (s2 == pick) + (s3 == pick) +
                (s4 == pick) + (s5 == pick) + (s6 == pick) + (s7 == pick);
        float v0 = GH(s0), v1 = GH(s1), v2 = GH(s2), v3 = GH(s3);
        float v4 = GH(s4), v5 = GH(s5), v6 = GH(s6), v7 = GH(s7);
        return (((v0 + v1) + (v2 + v3)) + ((v4 + v5) + (v6 + v7)));
      };
      int j = 0;
      for (; j + 8 <= d0; j += 8) { a0 += CHUNK8(j); if (LV1) c0 += cch; }
      for (; j < d0; ++j) {
        int s = __builtin_amdgcn_readlane(svm, j);
        if (LV1) c0 += (s == pick);
        a0 += GH(s);
      }
      for (; j + 8 <= dtot; j += 8) { a1 += CHUNK8(j); if (LV1) c1 += cch; }
      for (; j < dtot; ++j) {
        int s = __builtin_amdgcn_readlane(svm, j);
        if (LV1) c1 += (s == pick);
        a1 += GH(s);
      }
    } else {  // rare fallback: serial per-edge
      for (int e = beg0; e < beg0 + d0; ++e) {
        int s = sp[e];
        if (LV1) c0 += (s == pick);
        a0 += GH(s);
      }
      for (int e = beg0 + d0; e < beg0 + dtot; ++e) {
        int s = sp[e];
        if (LV1) c1 += (s == pick);
        a1 += GH(s);
      }
    }
    if (LV1) {
      a0 += (float)c0 * delta;
      a1 += (float)c1 * delta;
    }
    float acc0 = a0 * (d0 ? 1.0f / (float)d0 : 0.f);
    float acc1 = a1 * (d1 ? 1.0f / (float)d1 : 0.f);

    // interleaved matvec, 2 partials per row to break fma dependency chains
    float o0a = base[(size_t)i0 * Dd + lane] + cb, o0b = 0.f;
    float o1a = base[(size_t)i1 * Dd + lane] + cb, o1b = 0.f;
    if (i0 == pick) o0a += bp;
    if (i1 == pick) o1a += bp;
#pragma unroll
    for (int d = 0; d < Dd; d += 2) {
      float m0 = bcastf(acc0, d), m0b = bcastf(acc0, d + 1);
      float m1 = bcastf(acc1, d), m1b = bcastf(acc1, d + 1);
      o0a = fmaf(m0, wcol[d], o0a);
      o0b = fmaf(m0b, wcol[d + 1], o0b);
      o1a = fmaf(m1, wcol[d], o1a);
      o1b = fmaf(m1b, wcol[d + 1], o1b);
    }
    float out0 = fmaxf(o0a + o0b, 0.f);
    float out1 = fmaxf(o1a + o1b, 0.f);
    if (LV1) {
      hout16[(size_t)g * Nn * Dd + (size_t)i0 * Dd + lane] = __float2half(out0);
      hout16[(size_t)g * Nn * Dd + (size_t)i1 * Dd + lane] = __float2half(out1);
    } else {
      hout32[(size_t)g * Nn * Dd + (size_t)i0 * Dd + lane] = out0;
      hout32[(size_t)g * Nn * Dd + (size_t)i1 * Dd + lane] = out1;
      gs += out0 + out1;
    }
  }
  if (!LV1) atomicAdd(&gsum[g * Dd + lane], gs);
}

// K7: per-graph constants: cvec = g_embed@lin1_W[64:] + lin1_b ; u = lout_W@t ; c = lout_b.t
__global__ __launch_bounds__(128) void k_prep(
    const float* __restrict__ h, const float* __restrict__ gsum,
    const int* __restrict__ tgt, const float* __restrict__ lin1W,
    const float* __restrict__ lin1b, const float* __restrict__ loutW,
    const float* __restrict__ loutb, float* __restrict__ cvec,
    float* __restrict__ uvec, float* __restrict__ cscal) {
  int g = blockIdx.x;
  int k = threadIdx.x;
  __shared__ float tv[Dd], ge[Dd];
  if (k < Dd) {
    tv[k] = h[(size_t)g * Nn * Dd + (size_t)tgt[g] * Dd + k];
    ge[k] = gsum[g * Dd + k] * (1.0f / Nn);
  }
  __syncthreads();
  float cv = lin1b[k];
#pragma unroll 8
  for (int d = 0; d < Dd; ++d) cv = fmaf(ge[d], lin1W[(Dd + d) * Hh + k], cv);
  cvec[g * Hh + k] = cv;
  float uu = 0.f;
#pragma unroll 8
  for (int j = 0; j < Dd; ++j) uu = fmaf(loutW[k * Dd + j], tv[j], uu);
  uvec[g * Hh + k] = uu;
  if (k == 0) {
    float c = 0.f;
    for (int j = 0; j < Dd; ++j) c += loutb[j] * tv[j];
    cscal[g] = c;
  }
}

// K8: q[g,i] = sum_k relu(h_i . W1[:,k] + cvec[k]) * u[k] + c   (4 rows per wave)
__global__ __launch_bounds__(256) void k_final(
    const float* __restrict__ h, const float* __restrict__ lin1W,
    const float* __restrict__ cvec, const float* __restrict__ uvec,
    const float* __restrict__ cscal, float* __restrict__ out) {
  __shared__ float Wl[Dd * Hh];  // 32 KB: lin1_W rows 0..63
  int t = threadIdx.x;
  for (int i = t; i < Dd * Hh; i += 256) Wl[i] = lin1W[i];
  __syncthreads();
  int wv = t >> 6, lane = t & 63;
  int tot = Bg * Nn / 4;
  for (int p = blockIdx.x * 4 + wv; p < tot; p += gridDim.x * 4) {
    int row0 = p * 4;
    int g = row0 / Nn;
    int i0 = row0 - g * Nn;
    const float* hr = h + (size_t)g * Nn * Dd + (size_t)i0 * Dd;
    float ha = hr[lane], hb = hr[64 + lane], hc = hr[128 + lane], hd = hr[192 + lane];
    float c0 = cvec[g * Hh + lane], c1 = cvec[g * Hh + 64 + lane];
    float u0 = uvec[g * Hh + lane], u1 = uvec[g * Hh + 64 + lane];
    float za0 = c0, za1 = c1, zb0 = c0, zb1 = c1;
    float zc0 = c0, zc1 = c1, zd0 = c0, zd1 = c1;
#pragma unroll
    for (int d = 0; d < Dd; ++d) {
      float w0 = Wl[d * Hh + lane], w1 = Wl[d * Hh + 64 + lane];
      float a = bcastf(ha, d), b2 = bcastf(hb, d);
      float c2 = bcastf(hc, d), d2 = bcastf(hd, d);
      za0 = fmaf(a, w0, za0);  za1 = fmaf(a, w1, za1);
      zb0 = fmaf(b2, w0, zb0); zb1 = fmaf(b2, w1, zb1);
      zc0 = fmaf(c2, w0, zc0); zc1 = fmaf(c2, w1, zc1);
      zd0 = fmaf(d2, w0, zd0); zd1 = fmaf(d2, w1, zd1);
    }
    float s0 = fmaxf(za0, 0.f) * u0 + fmaxf(za1, 0.f) * u1;
    float s1 = fmaxf(zb0, 0.f) * u0 + fmaxf(zb1, 0.f) * u1;
    float s2 = fmaxf(zc0, 0.f) * u0 + fmaxf(zc1, 0.f) * u1;
    float s3 = fmaxf(zd0, 0.f) * u0 + fmaxf(zd1, 0.f) * u1;
#pragma unroll
    for (int off = 32; off; off >>= 1) {
      s0 += __shfl_xor(s0, off, 64);
      s1 += __shfl_xor(s1, off, 64);
      s2 += __shfl_xor(s2, off, 64);
      s3 += __shfl_xor(s3, off, 64);
    }
    if (lane == 0) {
      float cc = cscal[g];
      out[row0] = s0 + cc;
      out[row0 + 1] = s1 + cc;
      out[row0 + 2] = s2 + cc;
      out[row0 + 3] = s3 + cc;
    }
  }
}

extern "C" void kernel_launch(void* const* d_in, const int* in_sizes, int n_in,
                              void* d_out, int out_size, void* d_ws, size_t ws_size,
                              hipStream_t stream) {
  const float* node_features = (const float*)d_in[0];
  const float* w_n2l        = (const float*)d_in[1];
  const float* bias_n2l     = (const float*)d_in[2];
  const float* bias_picked  = (const float*)d_in[3];
  const float* conv_W       = (const float*)d_in[4];
  const float* conv_b       = (const float*)d_in[5];
  const float* lin1_W       = (const float*)d_in[6];
  const float* lin1_b       = (const float*)d_in[7];
  const float* lout_W       = (const float*)d_in[8];
  const float* lout_b       = (const float*)d_in[9];
  const int*   edges_src    = (const int*)d_in[11];
  const int*   edges_dst    = (const int*)d_in[12];
  const int*   target_nodes = (const int*)d_in[13];
  const int*   picked_nodes = (const int*)d_in[14];
  float* q_out = (float*)d_out;

  // workspace layout
  float*  base = (float*)d_ws;                           // N*D fp32
  __half* b16  = (__half*)(base + (size_t)Nn * Dd);      // N*D fp16
  __half* hAh  = b16 + (size_t)Nn * Dd;                  // B*N*D fp16
  float*  hB   = (float*)(hAh + (size_t)Bg * Nn * Dd);   // B*N*D fp32
  int*    deg  = (int*)(hB + (size_t)Bg * Nn * Dd);      // B*N
  int*    offs = deg + (size_t)Bg * Nn;                  // B*N
  int*    ssrc = offs + (size_t)Bg * Nn;                 // B*E
  float*  gsum = (float*)(ssrc + (size_t)Bg * Eg);       // B*64
  float*  cvec = gsum + Bg * Dd;                         // B*128
  float*  uvec = cvec + Bg * Hh;                         // B*128
  float*  csc  = uvec + Bg * Hh;                         // B

  hipMemsetAsync(deg, 0, (size_t)Bg * Nn * sizeof(int), stream);
  hipMemsetAsync(gsum, 0, (size_t)Bg * Dd * sizeof(float), stream);

  k_base<<<512, 256, 0, stream>>>(node_features, w_n2l, bias_n2l, base, b16);
  int eb = (Eg / 1024 + 1);  // 313 blocks/graph, 4 edges/thread
  k_hist<<<eb * Bg, 256, 0, stream>>>(edges_dst, deg);
  k_scan<<<Bg, 1024, 0, stream>>>(deg, offs);
  k_scatter<<<eb * Bg, 256, 0, stream>>>(edges_src, edges_dst, offs, ssrc);
  k_level<true><<<2048, 256, 0, stream>>>(b16, hB, hAh, base, conv_W, conv_b,
                                          bias_picked, picked_nodes, deg, offs,
                                          ssrc, gsum);
  k_level<false><<<2048, 256, 0, stream>>>(hAh, hB, hAh, base, conv_W, conv_b,
                                           bias_picked, picked_nodes, deg, offs,
                                           ssrc, gsum);
  k_prep<<<Bg, 128, 0, stream>>>(hB, gsum, target_nodes, lin1_W, lin1_b, lout_W,
                                 lout_b, cvec, uvec, csc);
  k_final<<<2048, 256, 0, stream>>>(hB, lin1_W, cvec, uvec, csc, q_out);
}

// Round 7
// 620.490 us; speedup vs baseline: 1.6983x; 1.0255x over previous
//
#include <hip/hip_runtime.h>
#include <hip/hip_bf16.h>
#include <hip/hip_fp16.h>

#define Nn 20000
#define NR 20001   // rows incl. trailing dummy zero row (for pad gathers)
#define Bg 8
#define Eg 320000
#define FDim 128
#define Dd 64
#define Hh 128

__device__ __forceinline__ float bcastf(float v, int l) {
  return __int_as_float(__builtin_amdgcn_readlane(__float_as_int(v), l));
}
__device__ __forceinline__ int bcasti(int v, int l) {
  return __builtin_amdgcn_readlane(v, l);
}

// K1: base = x @ w_n2l + bias ; b16 = fp16(relu(base)) (gather source, row Nn = 0);
//     b16p = fp16(base) (epilogue stream)
__global__ __launch_bounds__(256) void k_base(const float* __restrict__ x,
                                              const float* __restrict__ W,
                                              const float* __restrict__ b,
                                              float* __restrict__ base,
                                              __half* __restrict__ b16,
                                              __half* __restrict__ b16p) {
  __shared__ float Wl[FDim * Dd];   // 32 KB
  int t = threadIdx.x;
  for (int i = t; i < FDim * Dd; i += 256) Wl[i] = W[i];
  __syncthreads();
  int wv = t >> 6, lane = t & 63;
  float bias = b[lane];
  for (int row = blockIdx.x * 4 + wv; row < NR; row += gridDim.x * 4) {
    if (row == Nn) {  // dummy zero row for pad gathers
      b16[(size_t)row * Dd + lane] = __float2half(0.f);
      continue;
    }
    float x0 = x[row * FDim + lane];
    float x1 = x[row * FDim + 64 + lane];
    float acc = bias;
#pragma unroll
    for (int k = 0; k < 64; ++k) acc = fmaf(bcastf(x0, k), Wl[k * Dd + lane], acc);
#pragma unroll
    for (int k = 0; k < 64; ++k) acc = fmaf(bcastf(x1, k), Wl[(64 + k) * Dd + lane], acc);
    base[row * Dd + lane] = acc;
    b16[row * Dd + lane] = __float2half(fmaxf(acc, 0.f));
    b16p[row * Dd + lane] = __float2half(acc);
  }
}

// K2: per-graph dst-degree histogram, int4 (4 edges/thread), XCD-affine.
__global__ void k_hist(const int* __restrict__ dst, int* __restrict__ deg) {
  int g = blockIdx.x & 7;
  int c = blockIdx.x >> 3;
  int e4 = (c * 256 + threadIdx.x) * 4;
  if (e4 < Eg) {
    int4 d4 = *(const int4*)(dst + (size_t)g * Eg + e4);
    int* dp = deg + g * Nn;
    atomicAdd(&dp[d4.x], 1);
    atomicAdd(&dp[d4.y], 1);
    atomicAdd(&dp[d4.z], 1);
    atomicAdd(&dp[d4.w], 1);
  }
}

// K3: exclusive prefix-sum of deg -> offs (shfl-based, 4 syncs/chunk).
// Also zeroes the per-graph dummy row of hA.
__global__ __launch_bounds__(1024) void k_scan(const int* __restrict__ deg,
                                               int* __restrict__ offs,
                                               __half* __restrict__ hA) {
  int g = blockIdx.x;
  if (threadIdx.x < Dd)
    hA[((size_t)g * NR + Nn) * Dd + threadIdx.x] = __float2half(0.f);
  const int* dp = deg + g * Nn;
  int* op = offs + g * Nn;
  __shared__ int wsum[16];
  __shared__ int carrysh;
  if (threadIdx.x == 0) carrysh = 0;
  int lane = threadIdx.x & 63, wv = threadIdx.x >> 6;
  __syncthreads();
  for (int b0 = 0; b0 < Nn; b0 += 4096) {
    int gidx = b0 + threadIdx.x * 4;
    int4 v = make_int4(0, 0, 0, 0);
    bool ok = (gidx + 3 < Nn);
    if (ok) v = *(const int4*)(dp + gidx);
    int s0 = v.x, s1 = s0 + v.y, s2 = s1 + v.z, s3 = s2 + v.w;
    int incl = s3;
#pragma unroll
    for (int off = 1; off < 64; off <<= 1) {
      int y = __shfl_up(incl, off, 64);
      if (lane >= off) incl += y;
    }
    if (lane == 63) wsum[wv] = incl;
    __syncthreads();
    if (threadIdx.x < 16) {
      int w = wsum[threadIdx.x];
      int wincl = w;
#pragma unroll
      for (int off = 1; off < 16; off <<= 1) {
        int y = __shfl_up(wincl, off, 64);
        if (lane >= off) wincl += y;
      }
      wsum[threadIdx.x] = wincl - w;  // exclusive wave offset
    }
    __syncthreads();
    int cc = carrysh;
    int woff = wsum[wv];
    int excl = cc + woff + incl - s3;
    if (ok) {
      int4 o;
      o.x = excl; o.y = excl + s0; o.z = excl + s1; o.w = excl + s2;
      *(int4*)(op + gidx) = o;
    }
    __syncthreads();
    if (threadIdx.x == 1023) carrysh = cc + woff + incl;
    __syncthreads();
  }
}

// K4: counting-sort scatter, int4 reads (offs becomes END pointer). XCD-affine.
__global__ void k_scatter(const int* __restrict__ src, const int* __restrict__ dst,
                          int* __restrict__ offs, int* __restrict__ ssrc) {
  int g = blockIdx.x & 7;
  int c = blockIdx.x >> 3;
  int e4 = (c * 256 + threadIdx.x) * 4;
  if (e4 < Eg) {
    size_t be = (size_t)g * Eg + e4;
    int4 d4 = *(const int4*)(dst + be);
    int4 s4 = *(const int4*)(src + be);
    int* op = offs + g * Nn;
    int* sp = ssrc + (size_t)g * Eg;
    sp[atomicAdd(&op[d4.x], 1)] = s4.x;
    sp[atomicAdd(&op[d4.y], 1)] = s4.y;
    sp[atomicAdd(&op[d4.z], 1)] = s4.z;
    sp[atomicAdd(&op[d4.w], 1)] = s4.w;
  }
}

// K5: fused SpMM + conv matvec + relu. Row PAIR per wave, branch-free padded
// chunks (pad lanes gather the zeroed dummy row Nn). conv_W column in VGPRs.
template <bool LV1>
__global__ __launch_bounds__(256, 3) void k_level(
    const __half* __restrict__ gsrc,   // LV1: shared b16 (NR rows); else hA (B*NR rows)
    float* __restrict__ hout32,
    __half* __restrict__ hout16,
    const float* __restrict__ base,
    const __half* __restrict__ b16p,
    const float* __restrict__ convW, const float* __restrict__ convb,
    const float* __restrict__ biasp, const int* __restrict__ picked,
    const int* __restrict__ deg, const int* __restrict__ offs,
    const int* __restrict__ ssrc, float* __restrict__ gsum) {
  int t = threadIdx.x;
  int wv = t >> 6, lane = t & 63;
  float wcol[Dd];  // conv_W column `lane` in registers
#pragma unroll
  for (int d = 0; d < Dd; ++d) wcol[d] = convW[d * Dd + lane];
  float cb = convb[lane];
  float bp = biasp[lane];
  int g = blockIdx.x & 7;
  int lb = blockIdx.x >> 3;
  int pstride = (gridDim.x >> 3) * 4;
  int pick = picked[g];
  int gN = g * Nn;
  const int* sp = ssrc + (size_t)g * Eg;
  const __half* hsrc = LV1 ? gsrc : (gsrc + (size_t)g * NR * Dd);
  float delta = 0.f;
  if (LV1) {
    float db = base[(size_t)pick * Dd + lane];
    float d16 = __half2float(__float2half(fmaxf(db, 0.f)));
    delta = fmaxf(db + bp, 0.f) - d16;  // true pick row minus stored b16 row
  }
  float gs = 0.f;

  for (int p = lb * 4 + wv; p < Nn / 2; p += pstride) {
    int i0 = p * 2, i1 = i0 + 1;
    int2 dg2 = *(const int2*)&deg[gN + i0];
    int d0 = dg2.x, dtot = d0 + dg2.y;
    int end0 = offs[gN + i0];
    int beg0 = end0 - d0;

    float a0 = 0.f, aT = 0.f;
    int c0cnt = 0, cTcnt = 0;
    if (dtot <= 64) {
      int svm = Nn;  // dummy (zero row) for pad lanes
      if (lane < dtot) svm = sp[beg0 + lane];  // one coalesced index load, both rows
      int nch = (dtot + 7) >> 3;
      for (int c = 0; c < nch; ++c) {
        int j = c * 8;
        int s0 = bcasti(svm, j + 0), s1 = bcasti(svm, j + 1);
        int s2 = bcasti(svm, j + 2), s3 = bcasti(svm, j + 3);
        int s4 = bcasti(svm, j + 4), s5 = bcasti(svm, j + 5);
        int s6 = bcasti(svm, j + 6), s7 = bcasti(svm, j + 7);
        float v0 = __half2float(hsrc[((unsigned)s0 << 6) + lane]);
        float v1 = __half2float(hsrc[((unsigned)s1 << 6) + lane]);
        float v2 = __half2float(hsrc[((unsigned)s2 << 6) + lane]);
        float v3 = __half2float(hsrc[((unsigned)s3 << 6) + lane]);
        float v4 = __half2float(hsrc[((unsigned)s4 << 6) + lane]);
        float v5 = __half2float(hsrc[((unsigned)s5 << 6) + lane]);
        float v6 = __half2float(hsrc[((unsigned)s6 << 6) + lane]);
        float v7 = __half2float(hsrc[((unsigned)s7 << 6) + lane]);
        if (LV1) {
          cTcnt += (s0 == pick) + (s1 == pick) + (s2 == pick) + (s3 == pick) +
                   (s4 == pick) + (s5 == pick) + (s6 == pick) + (s7 == pick);
          c0cnt += ((j + 0 < d0) & (s0 == pick)) + ((j + 1 < d0) & (s1 == pick)) +
                   ((j + 2 < d0) & (s2 == pick)) + ((j + 3 < d0) & (s3 == pick)) +
                   ((j + 4 < d0) & (s4 == pick)) + ((j + 5 < d0) & (s5 == pick)) +
                   ((j + 6 < d0) & (s6 == pick)) + ((j + 7 < d0) & (s7 == pick));
        }
        float cs = ((v0 + v1) + (v2 + v3)) + ((v4 + v5) + (v6 + v7));
        aT += cs;  // pads contribute exactly 0 (dummy zero row)
        if (j + 8 <= d0) {
          a0 += cs;
        } else if (j < d0) {  // the single row0/row1 boundary chunk
          int r = d0 - j;  // 1..7
          float pfx = (r > 0 ? v0 : 0.f) + (r > 1 ? v1 : 0.f) + (r > 2 ? v2 : 0.f) +
                      (r > 3 ? v3 : 0.f) + (r > 4 ? v4 : 0.f) + (r > 5 ? v5 : 0.f) +
                      (r > 6 ? v6 : 0.f);
          a0 += pfx;
        }
      }
    } else {  // rare fallback: serial per-edge
      for (int e = beg0; e < end0; ++e) {
        int s = sp[e];
        if (LV1) c0cnt += (s == pick);
        a0 += __half2float(hsrc[((unsigned)s << 6) + lane]);
      }
      aT = a0;
      int end1 = beg0 + dtot;
      for (int e = end0; e < end1; ++e) {
        int s = sp[e];
        if (LV1) cTcnt += (s == pick);
        aT += __half2float(hsrc[((unsigned)s << 6) + lane]);
      }
      if (LV1) cTcnt += c0cnt;
    }
    if (LV1) {
      a0 += (float)c0cnt * delta;
      aT += (float)cTcnt * delta;
    }
    float a1 = aT - a0;
    float acc0 = a0 * (d0 ? 1.0f / (float)d0 : 0.f);
    float acc1 = a1 * (dg2.y ? 1.0f / (float)dg2.y : 0.f);

    float o0a = __half2float(b16p[(size_t)i0 * Dd + lane]) + cb, o0b = 0.f;
    float o1a = __half2float(b16p[(size_t)i1 * Dd + lane]) + cb, o1b = 0.f;
    if (i0 == pick) o0a += bp;
    if (i1 == pick) o1a += bp;
#pragma unroll
    for (int d = 0; d < Dd; d += 2) {
      o0a = fmaf(bcastf(acc0, d), wcol[d], o0a);
      o0b = fmaf(bcastf(acc0, d + 1), wcol[d + 1], o0b);
      o1a = fmaf(bcastf(acc1, d), wcol[d], o1a);
      o1b = fmaf(bcastf(acc1, d + 1), wcol[d + 1], o1b);
    }
    float out0 = fmaxf(o0a + o0b, 0.f);
    float out1 = fmaxf(o1a + o1b, 0.f);
    if (LV1) {
      size_t ob = (size_t)g * NR * Dd;
      hout16[ob + (size_t)i0 * Dd + lane] = __float2half(out0);
      hout16[ob + (size_t)i1 * Dd + lane] = __float2half(out1);
    } else {
      hout32[(size_t)g * Nn * Dd + (size_t)i0 * Dd + lane] = out0;
      hout32[(size_t)g * Nn * Dd + (size_t)i1 * Dd + lane] = out1;
      gs += out0 + out1;
    }
  }
  if (!LV1) atomicAdd(&gsum[g * Dd + lane], gs);
}

// K7: per-graph constants: cvec = g_embed@lin1_W[64:] + lin1_b ; u = lout_W@t ; c = lout_b.t
__global__ __launch_bounds__(128) void k_prep(
    const float* __restrict__ h, const float* __restrict__ gsum,
    const int* __restrict__ tgt, const float* __restrict__ lin1W,
    const float* __restrict__ lin1b, const float* __restrict__ loutW,
    const float* __restrict__ loutb, float* __restrict__ cvec,
    float* __restrict__ uvec, float* __restrict__ cscal) {
  int g = blockIdx.x;
  int k = threadIdx.x;
  __shared__ float tv[Dd], ge[Dd];
  if (k < Dd) {
    tv[k] = h[(size_t)g * Nn * Dd + (size_t)tgt[g] * Dd + k];
    ge[k] = gsum[g * Dd + k] * (1.0f / Nn);
  }
  __syncthreads();
  float cv = lin1b[k];
#pragma unroll 8
  for (int d = 0; d < Dd; ++d) cv = fmaf(ge[d], lin1W[(Dd + d) * Hh + k], cv);
  cvec[g * Hh + k] = cv;
  float uu = 0.f;
#pragma unroll 8
  for (int j = 0; j < Dd; ++j) uu = fmaf(loutW[k * Dd + j], tv[j], uu);
  uvec[g * Hh + k] = uu;
  if (k == 0) {
    float c = 0.f;
    for (int j = 0; j < Dd; ++j) c += loutb[j] * tv[j];
    cscal[g] = c;
  }
}

// K8: q[g,i] = sum_k relu(h_i . W1[:,k] + cvec[k]) * u[k] + c   (4 rows per wave)
__global__ __launch_bounds__(256) void k_final(
    const float* __restrict__ h, const float* __restrict__ lin1W,
    const float* __restrict__ cvec, const float* __restrict__ uvec,
    const float* __restrict__ cscal, float* __restrict__ out) {
  __shared__ float Wl[Dd * Hh];  // 32 KB: lin1_W rows 0..63
  int t = threadIdx.x;
  for (int i = t; i < Dd * Hh; i += 256) Wl[i] = lin1W[i];
  __syncthreads();
  int wv = t >> 6, lane = t & 63;
  int tot = Bg * Nn / 4;
  for (int p = blockIdx.x * 4 + wv; p < tot; p += gridDim.x * 4) {
    int row0 = p * 4;
    int g = row0 / Nn;
    int i0 = row0 - g * Nn;
    const float* hr = h + (size_t)g * Nn * Dd + (size_t)i0 * Dd;
    float ha = hr[lane], hb = hr[64 + lane], hc = hr[128 + lane], hd = hr[192 + lane];
    float c0 = cvec[g * Hh + lane], c1 = cvec[g * Hh + 64 + lane];
    float u0 = uvec[g * Hh + lane], u1 = uvec[g * Hh + 64 + lane];
    float za0 = c0, za1 = c1, zb0 = c0, zb1 = c1;
    float zc0 = c0, zc1 = c1, zd0 = c0, zd1 = c1;
#pragma unroll
    for (int d = 0; d < Dd; ++d) {
      float w0 = Wl[d * Hh + lane], w1 = Wl[d * Hh + 64 + lane];
      float a = bcastf(ha, d), b2 = bcastf(hb, d);
      float c2 = bcastf(hc, d), d2 = bcastf(hd, d);
      za0 = fmaf(a, w0, za0);  za1 = fmaf(a, w1, za1);
      zb0 = fmaf(b2, w0, zb0); zb1 = fmaf(b2, w1, zb1);
      zc0 = fmaf(c2, w0, zc0); zc1 = fmaf(c2, w1, zc1);
      zd0 = fmaf(d2, w0, zd0); zd1 = fmaf(d2, w1, zd1);
    }
    float s0 = fmaxf(za0, 0.f) * u0 + fmaxf(za1, 0.f) * u1;
    float s1 = fmaxf(zb0, 0.f) * u0 + fmaxf(zb1, 0.f) * u1;
    float s2 = fmaxf(zc0, 0.f) * u0 + fmaxf(zc1, 0.f) * u1;
    float s3 = fmaxf(zd0, 0.f) * u0 + fmaxf(zd1, 0.f) * u1;
#pragma unroll
    for (int off = 32; off; off >>= 1) {
      s0 += __shfl_xor(s0, off, 64);
      s1 += __shfl_xor(s1, off, 64);
      s2 += __shfl_xor(s2, off, 64);
      s3 += __shfl_xor(s3, off, 64);
    }
    if (lane == 0) {
      float cc = cscal[g];
      out[row0] = s0 + cc;
      out[row0 + 1] = s1 + cc;
      out[row0 + 2] = s2 + cc;
      out[row0 + 3] = s3 + cc;
    }
  }
}

extern "C" void kernel_launch(void* const* d_in, const int* in_sizes, int n_in,
                              void* d_out, int out_size, void* d_ws, size_t ws_size,
                              hipStream_t stream) {
  const float* node_features = (const float*)d_in[0];
  const float* w_n2l        = (const float*)d_in[1];
  const float* bias_n2l     = (const float*)d_in[2];
  const float* bias_picked  = (const float*)d_in[3];
  const float* conv_W       = (const float*)d_in[4];
  const float* conv_b       = (const float*)d_in[5];
  const float* lin1_W       = (const float*)d_in[6];
  const float* lin1_b       = (const float*)d_in[7];
  const float* lout_W       = (const float*)d_in[8];
  const float* lout_b       = (const float*)d_in[9];
  const int*   edges_src    = (const int*)d_in[11];
  const int*   edges_dst    = (const int*)d_in[12];
  const int*   target_nodes = (const int*)d_in[13];
  const int*   picked_nodes = (const int*)d_in[14];
  float* q_out = (float*)d_out;

  // workspace layout
  float*  base = (float*)d_ws;                           // N*D fp32
  __half* b16  = (__half*)(base + (size_t)Nn * Dd);      // NR*D fp16 (relu'd)
  __half* b16p = b16 + (size_t)NR * Dd;                  // N*D fp16 (pre-relu)
  __half* hAh  = b16p + (size_t)Nn * Dd;                 // B*NR*D fp16
  float*  hB   = (float*)(hAh + (size_t)Bg * NR * Dd);   // B*N*D fp32
  int*    deg  = (int*)(hB + (size_t)Bg * Nn * Dd);      // B*N
  int*    offs = deg + (size_t)Bg * Nn;                  // B*N
  int*    ssrc = offs + (size_t)Bg * Nn;                 // B*E
  float*  gsum = (float*)(ssrc + (size_t)Bg * Eg);       // B*64
  float*  cvec = gsum + Bg * Dd;                         // B*128
  float*  uvec = cvec + Bg * Hh;                         // B*128
  float*  csc  = uvec + Bg * Hh;                         // B

  hipMemsetAsync(deg, 0, (size_t)Bg * Nn * sizeof(int), stream);
  hipMemsetAsync(gsum, 0, (size_t)Bg * Dd * sizeof(float), stream);

  k_base<<<512, 256, 0, stream>>>(node_features, w_n2l, bias_n2l, base, b16, b16p);
  int eb = (Eg / 1024 + 1);  // 313 blocks/graph, 4 edges/thread
  k_hist<<<eb * Bg, 256, 0, stream>>>(edges_dst, deg);
  k_scan<<<Bg, 1024, 0, stream>>>(deg, offs, hAh);
  k_scatter<<<eb * Bg, 256, 0, stream>>>(edges_src, edges_dst, offs, ssrc);
  k_level<true><<<2048, 256, 0, stream>>>(b16, hB, hAh, base, b16p, conv_W, conv_b,
                                          bias_picked, picked_nodes, deg, offs,
                                          ssrc, gsum);
  k_level<false><<<2048, 256, 0, stream>>>(hAh, hB, hAh, base, b16p, conv_W, conv_b,
                                           bias_picked, picked_nodes, deg, offs,
                                           ssrc, gsum);
  k_prep<<<Bg, 128, 0, stream>>>(hB, gsum, target_nodes, lin1_W, lin1_b, lout_W,
                                 lout_b, cvec, uvec, csc);
  k_final<<<2048, 256, 0, stream>>>(hB, lin1_W, cvec, uvec, csc, q_out);
}

// Round 8
// 549.527 us; speedup vs baseline: 1.9177x; 1.1291x over previous
//
#include <hip/hip_runtime.h>
#include <hip/hip_bf16.h>
#include <hip/hip_fp16.h>

#define Nn 20000
#define NR 20001   // rows incl. trailing dummy zero row (for pad gathers)
#define Bg 8
#define Eg 320000
#define FDim 128
#define Dd 64
#define Hh 128

typedef _Float16 v2h __attribute__((ext_vector_type(2)));

__device__ __forceinline__ float bcastf(float v, int l) {
  return __int_as_float(__builtin_amdgcn_readlane(__float_as_int(v), l));
}
__device__ __forceinline__ int bcasti(int v, int l) {
  return __builtin_amdgcn_readlane(v, l);
}
__device__ __forceinline__ v2h u2h2(unsigned u) { return __builtin_bit_cast(v2h, u); }
__device__ __forceinline__ unsigned h22u(__half2 h) { return __builtin_bit_cast(unsigned, h); }
__device__ __forceinline__ float fdot2f(v2h a, v2h b, float c) {
  return __builtin_amdgcn_fdot2(a, b, c, false);
}

// K1: base = x @ w_n2l + bias ; b16 = fp16(relu(base)) (gather source, row Nn = 0);
//     b16p = fp16(base) (epilogue stream)
__global__ __launch_bounds__(256) void k_base(const float* __restrict__ x,
                                              const float* __restrict__ W,
                                              const float* __restrict__ b,
                                              float* __restrict__ base,
                                              __half* __restrict__ b16,
                                              __half* __restrict__ b16p) {
  __shared__ float Wl[FDim * Dd];   // 32 KB
  int t = threadIdx.x;
  for (int i = t; i < FDim * Dd; i += 256) Wl[i] = W[i];
  __syncthreads();
  int wv = t >> 6, lane = t & 63;
  float bias = b[lane];
  for (int row = blockIdx.x * 4 + wv; row < NR; row += gridDim.x * 4) {
    if (row == Nn) {  // dummy zero row for pad gathers
      b16[(size_t)row * Dd + lane] = __float2half(0.f);
      continue;
    }
    float x0 = x[row * FDim + lane];
    float x1 = x[row * FDim + 64 + lane];
    float acc = bias;
#pragma unroll
    for (int k = 0; k < 64; ++k) acc = fmaf(bcastf(x0, k), Wl[k * Dd + lane], acc);
#pragma unroll
    for (int k = 0; k < 64; ++k) acc = fmaf(bcastf(x1, k), Wl[(64 + k) * Dd + lane], acc);
    base[row * Dd + lane] = acc;
    b16[row * Dd + lane] = __float2half(fmaxf(acc, 0.f));
    b16p[row * Dd + lane] = __float2half(acc);
  }
}

// K2: per-graph dst-degree histogram, int4 (4 edges/thread), XCD-affine.
__global__ void k_hist(const int* __restrict__ dst, int* __restrict__ deg) {
  int g = blockIdx.x & 7;
  int c = blockIdx.x >> 3;
  int e4 = (c * 256 + threadIdx.x) * 4;
  if (e4 < Eg) {
    int4 d4 = *(const int4*)(dst + (size_t)g * Eg + e4);
    int* dp = deg + g * Nn;
    atomicAdd(&dp[d4.x], 1);
    atomicAdd(&dp[d4.y], 1);
    atomicAdd(&dp[d4.z], 1);
    atomicAdd(&dp[d4.w], 1);
  }
}

// K3: exclusive prefix-sum of deg -> offs (shfl-based). Zeroes dummy row of hA.
__global__ __launch_bounds__(1024) void k_scan(const int* __restrict__ deg,
                                               int* __restrict__ offs,
                                               __half* __restrict__ hA) {
  int g = blockIdx.x;
  if (threadIdx.x < Dd)
    hA[((size_t)g * NR + Nn) * Dd + threadIdx.x] = __float2half(0.f);
  const int* dp = deg + g * Nn;
  int* op = offs + g * Nn;
  __shared__ int wsum[16];
  __shared__ int carrysh;
  if (threadIdx.x == 0) carrysh = 0;
  int lane = threadIdx.x & 63, wv = threadIdx.x >> 6;
  __syncthreads();
  for (int b0 = 0; b0 < Nn; b0 += 4096) {
    int gidx = b0 + threadIdx.x * 4;
    int4 v = make_int4(0, 0, 0, 0);
    bool ok = (gidx + 3 < Nn);
    if (ok) v = *(const int4*)(dp + gidx);
    int s0 = v.x, s1 = s0 + v.y, s2 = s1 + v.z, s3 = s2 + v.w;
    int incl = s3;
#pragma unroll
    for (int off = 1; off < 64; off <<= 1) {
      int y = __shfl_up(incl, off, 64);
      if (lane >= off) incl += y;
    }
    if (lane == 63) wsum[wv] = incl;
    __syncthreads();
    if (threadIdx.x < 16) {
      int w = wsum[threadIdx.x];
      int wincl = w;
#pragma unroll
      for (int off = 1; off < 16; off <<= 1) {
        int y = __shfl_up(wincl, off, 64);
        if (lane >= off) wincl += y;
      }
      wsum[threadIdx.x] = wincl - w;  // exclusive wave offset
    }
    __syncthreads();
    int cc = carrysh;
    int woff = wsum[wv];
    int excl = cc + woff + incl - s3;
    if (ok) {
      int4 o;
      o.x = excl; o.y = excl + s0; o.z = excl + s1; o.w = excl + s2;
      *(int4*)(op + gidx) = o;
    }
    __syncthreads();
    if (threadIdx.x == 1023) carrysh = cc + woff + incl;
    __syncthreads();
  }
}

// K4: counting-sort scatter, int4 reads (offs becomes END pointer). XCD-affine.
__global__ void k_scatter(const int* __restrict__ src, const int* __restrict__ dst,
                          int* __restrict__ offs, int* __restrict__ ssrc) {
  int g = blockIdx.x & 7;
  int c = blockIdx.x >> 3;
  int e4 = (c * 256 + threadIdx.x) * 4;
  if (e4 < Eg) {
    size_t be = (size_t)g * Eg + e4;
    int4 d4 = *(const int4*)(dst + be);
    int4 s4 = *(const int4*)(src + be);
    int* op = offs + g * Nn;
    int* sp = ssrc + (size_t)g * Eg;
    sp[atomicAdd(&op[d4.x], 1)] = s4.x;
    sp[atomicAdd(&op[d4.y], 1)] = s4.y;
    sp[atomicAdd(&op[d4.z], 1)] = s4.z;
    sp[atomicAdd(&op[d4.w], 1)] = s4.w;
  }
}

// K5: fused SpMM + conv matvec (v_dot2_f32_f16, conv_W packed in 32 pinned
// VGPRs) + relu. Row PAIR per wave; ballot-based pick counting in LV1.
template <bool LV1>
__global__ __launch_bounds__(256, 4) void k_level(
    const __half* __restrict__ gsrc,   // LV1: b16 (NR rows); LV2: hA (B*NR rows)
    __half* __restrict__ hout,         // LV1: hA (NR stride); LV2: h2 (Nn stride)
    const float* __restrict__ base,
    const __half* __restrict__ b16p,
    const float* __restrict__ convW, const float* __restrict__ convb,
    const float* __restrict__ biasp, const int* __restrict__ picked,
    const int* __restrict__ deg, const int* __restrict__ offs,
    const int* __restrict__ ssrc, float* __restrict__ gsum) {
  int t = threadIdx.x;
  int wv = t >> 6, lane = t & 63;
  // conv_W column `lane`, packed (d,d+1) pairs -> 32 VGPRs, pinned vs remat
  unsigned wc[32];
#pragma unroll
  for (int d2 = 0; d2 < 32; ++d2)
    wc[d2] = h22u(__floats2half2_rn(convW[(2 * d2) * Dd + lane],
                                    (convW[(2 * d2 + 1) * Dd + lane])));
#pragma unroll
  for (int d2 = 0; d2 < 32; ++d2) asm volatile("" : "+v"(wc[d2]));
  float cb = convb[lane];
  float bp = biasp[lane];
  int g = blockIdx.x & 7;
  int lb = blockIdx.x >> 3;
  int pstride = (gridDim.x >> 3) * 4;
  int pick = picked[g];
  int gN = g * Nn;
  const int* sp = ssrc + (size_t)g * Eg;
  const __half* hsrc = LV1 ? gsrc : (gsrc + (size_t)g * NR * Dd);
  __half* outp = LV1 ? (hout + (size_t)g * NR * Dd) : (hout + (size_t)g * Nn * Dd);
  float delta = 0.f;
  if (LV1) {
    float db = base[(size_t)pick * Dd + lane];
    float d16 = __half2float(__float2half(fmaxf(db, 0.f)));
    delta = fmaxf(db + bp, 0.f) - d16;  // true pick row minus stored b16 row
  }
  float gs = 0.f;

  for (int p = lb * 4 + wv; p < Nn / 2; p += pstride) {
    int i0 = p * 2, i1 = i0 + 1;
    int2 dg2 = *(const int2*)&deg[gN + i0];
    int d0 = dg2.x, dtot = d0 + dg2.y;
    int end0 = offs[gN + i0];
    int beg0 = end0 - d0;

    float a0 = 0.f, aT = 0.f;
    if (dtot <= 64) {
      int svm = Nn;  // dummy (zero row) for pad lanes
      if (lane < dtot) svm = sp[beg0 + lane];  // one coalesced index load
      if (LV1) {
        unsigned long long pm = __ballot(svm == pick);
        unsigned long long m0 = (d0 >= 64) ? ~0ull : ((1ull << d0) - 1ull);
        a0 += (float)__popcll(pm & m0) * delta;
        aT += (float)__popcll(pm) * delta;
      }
      int nch = (dtot + 7) >> 3;
      for (int c = 0; c < nch; ++c) {
        int j = c * 8;
        int s0 = bcasti(svm, j + 0), s1 = bcasti(svm, j + 1);
        int s2 = bcasti(svm, j + 2), s3 = bcasti(svm, j + 3);
        int s4 = bcasti(svm, j + 4), s5 = bcasti(svm, j + 5);
        int s6 = bcasti(svm, j + 6), s7 = bcasti(svm, j + 7);
        float v0 = __half2float(hsrc[((unsigned)s0 << 6) + lane]);
        float v1 = __half2float(hsrc[((unsigned)s1 << 6) + lane]);
        float v2 = __half2float(hsrc[((unsigned)s2 << 6) + lane]);
        float v3 = __half2float(hsrc[((unsigned)s3 << 6) + lane]);
        float v4 = __half2float(hsrc[((unsigned)s4 << 6) + lane]);
        float v5 = __half2float(hsrc[((unsigned)s5 << 6) + lane]);
        float v6 = __half2float(hsrc[((unsigned)s6 << 6) + lane]);
        float v7 = __half2float(hsrc[((unsigned)s7 << 6) + lane]);
        float cs = ((v0 + v1) + (v2 + v3)) + ((v4 + v5) + (v6 + v7));
        aT += cs;  // pads contribute exactly 0 (dummy zero row)
        if (j + 8 <= d0) {
          a0 += cs;
        } else if (j < d0) {  // the single row0/row1 boundary chunk
          int r = d0 - j;  // 1..7
          float pfx = (r > 0 ? v0 : 0.f) + (r > 1 ? v1 : 0.f) + (r > 2 ? v2 : 0.f) +
                      (r > 3 ? v3 : 0.f) + (r > 4 ? v4 : 0.f) + (r > 5 ? v5 : 0.f) +
                      (r > 6 ? v6 : 0.f);
          a0 += pfx;
        }
      }
    } else {  // rare fallback: serial per-edge
      int c0cnt = 0, cTcnt = 0;
      for (int e = beg0; e < end0; ++e) {
        int s = sp[e];
        if (LV1) c0cnt += (s == pick);
        a0 += __half2float(hsrc[((unsigned)s << 6) + lane]);
      }
      aT = a0;
      int end1 = beg0 + dtot;
      for (int e = end0; e < end1; ++e) {
        int s = sp[e];
        if (LV1) cTcnt += (s == pick);
        aT += __half2float(hsrc[((unsigned)s << 6) + lane]);
      }
      if (LV1) {
        a0 += (float)c0cnt * delta;
        aT += (float)(cTcnt + c0cnt) * delta;
      }
    }
    float a1 = aT - a0;
    float acc0 = a0 * (d0 ? 1.0f / (float)d0 : 0.f);
    float acc1 = a1 * (dg2.y ? 1.0f / (float)dg2.y : 0.f);

    // pack (acc[2k], acc[2k+1]) into lane k's half2 -> readlane broadcasts pairs
    unsigned p0 = h22u(__floats2half2_rn(acc0, __shfl_down(acc0, 1, 64)));
    unsigned p1 = h22u(__floats2half2_rn(acc1, __shfl_down(acc1, 1, 64)));

    float o0a = __half2float(b16p[(size_t)i0 * Dd + lane]) + cb, o0b = 0.f;
    float o1a = __half2float(b16p[(size_t)i1 * Dd + lane]) + cb, o1b = 0.f;
    if (i0 == pick) o0a += bp;
    if (i1 == pick) o1a += bp;
#pragma unroll
    for (int d2 = 0; d2 < 32; d2 += 2) {
      v2h m00 = u2h2(bcasti(p0, 2 * d2)),     m01 = u2h2(bcasti(p0, 2 * d2 + 2));
      v2h m10 = u2h2(bcasti(p1, 2 * d2)),     m11 = u2h2(bcasti(p1, 2 * d2 + 2));
      o0a = fdot2f(m00, u2h2(wc[d2]), o0a);
      o0b = fdot2f(m01, u2h2(wc[d2 + 1]), o0b);
      o1a = fdot2f(m10, u2h2(wc[d2]), o1a);
      o1b = fdot2f(m11, u2h2(wc[d2 + 1]), o1b);
    }
    float out0 = fmaxf(o0a + o0b, 0.f);
    float out1 = fmaxf(o1a + o1b, 0.f);
    outp[(size_t)i0 * Dd + lane] = __float2half(out0);
    outp[(size_t)i1 * Dd + lane] = __float2half(out1);
    if (!LV1) gs += out0 + out1;
  }
  if (!LV1) atomicAdd(&gsum[g * Dd + lane], gs);
}

// K7: per-graph constants: cvec = g_embed@lin1_W[64:] + lin1_b ; u = lout_W@t ; c = lout_b.t
__global__ __launch_bounds__(128) void k_prep(
    const __half* __restrict__ h2, const float* __restrict__ gsum,
    const int* __restrict__ tgt, const float* __restrict__ lin1W,
    const float* __restrict__ lin1b, const float* __restrict__ loutW,
    const float* __restrict__ loutb, float* __restrict__ cvec,
    float* __restrict__ uvec, float* __restrict__ cscal) {
  int g = blockIdx.x;
  int k = threadIdx.x;
  __shared__ float tv[Dd], ge[Dd];
  if (k < Dd) {
    tv[k] = __half2float(h2[(size_t)g * Nn * Dd + (size_t)tgt[g] * Dd + k]);
    ge[k] = gsum[g * Dd + k] * (1.0f / Nn);
  }
  __syncthreads();
  float cv = lin1b[k];
#pragma unroll 8
  for (int d = 0; d < Dd; ++d) cv = fmaf(ge[d], lin1W[(Dd + d) * Hh + k], cv);
  cvec[g * Hh + k] = cv;
  float uu = 0.f;
#pragma unroll 8
  for (int j = 0; j < Dd; ++j) uu = fmaf(loutW[k * Dd + j], tv[j], uu);
  uvec[g * Hh + k] = uu;
  if (k == 0) {
    float c = 0.f;
    for (int j = 0; j < Dd; ++j) c += loutb[j] * tv[j];
    cscal[g] = c;
  }
}

// K8: q[g,i] = sum_k relu(h_i . W1[:,k] + cvec[k]) * u[k] + c
// 4 rows/wave, fp16 h2 + half2 LDS W1 + v_dot2_f32_f16.
__global__ __launch_bounds__(256) void k_final(
    const __half* __restrict__ h2, const float* __restrict__ lin1W,
    const float* __restrict__ cvec, const float* __restrict__ uvec,
    const float* __restrict__ cscal, float* __restrict__ out) {
  __shared__ unsigned Wl2[32 * Hh];  // 16 KB: (W1[2d2][c], W1[2d2+1][c]) pairs
  int t = threadIdx.x;
  for (int i = t; i < 32 * Hh; i += 256) {
    int d2 = i >> 7, c = i & 127;
    Wl2[i] = h22u(__floats2half2_rn(lin1W[(2 * d2) * Hh + c],
                                    lin1W[(2 * d2 + 1) * Hh + c]));
  }
  __syncthreads();
  int wv = t >> 6, lane = t & 63;
  int lr = lane & 31, hi = lane >> 5;
  int tot = Bg * Nn / 4;
  for (int p = blockIdx.x * 4 + wv; p < tot; p += gridDim.x * 4) {
    int row0 = p * 4;
    int g = row0 / Nn;
    int i0 = row0 - g * Nn;
    const __half2* hb = (const __half2*)(h2 + (size_t)g * Nn * Dd);
    // ra: rows i0 (lanes 0-31) / i0+1 (lanes 32-63); rb: i0+2 / i0+3
    unsigned ra = h22u(hb[(size_t)(i0 + hi) * 32 + lr]);
    unsigned rb = h22u(hb[(size_t)(i0 + 2 + hi) * 32 + lr]);
    float c0 = cvec[g * Hh + lane], c1 = cvec[g * Hh + 64 + lane];
    float u0 = uvec[g * Hh + lane], u1 = uvec[g * Hh + 64 + lane];
    float za0 = c0, za1 = c1, zb0 = c0, zb1 = c1;
    float zc0 = c0, zc1 = c1, zd0 = c0, zd1 = c1;
#pragma unroll
    for (int d2 = 0; d2 < 32; ++d2) {
      v2h w0 = u2h2(Wl2[d2 * Hh + lane]);
      v2h w1 = u2h2(Wl2[d2 * Hh + 64 + lane]);
      v2h a0 = u2h2(bcasti(ra, d2)), a1 = u2h2(bcasti(ra, 32 + d2));
      v2h b0 = u2h2(bcasti(rb, d2)), b1 = u2h2(bcasti(rb, 32 + d2));
      za0 = fdot2f(a0, w0, za0);  za1 = fdot2f(a0, w1, za1);
      zb0 = fdot2f(a1, w0, zb0);  zb1 = fdot2f(a1, w1, zb1);
      zc0 = fdot2f(b0, w0, zc0);  zc1 = fdot2f(b0, w1, zc1);
      zd0 = fdot2f(b1, w0, zd0);  zd1 = fdot2f(b1, w1, zd1);
    }
    float s0 = fmaxf(za0, 0.f) * u0 + fmaxf(za1, 0.f) * u1;
    float s1 = fmaxf(zb0, 0.f) * u0 + fmaxf(zb1, 0.f) * u1;
    float s2 = fmaxf(zc0, 0.f) * u0 + fmaxf(zc1, 0.f) * u1;
    float s3 = fmaxf(zd0, 0.f) * u0 + fmaxf(zd1, 0.f) * u1;
#pragma unroll
    for (int off = 32; off; off >>= 1) {
      s0 += __shfl_xor(s0, off, 64);
      s1 += __shfl_xor(s1, off, 64);
      s2 += __shfl_xor(s2, off, 64);
      s3 += __shfl_xor(s3, off, 64);
    }
    if (lane == 0) {
      float cc = cscal[g];
      out[row0] = s0 + cc;
      out[row0 + 1] = s1 + cc;
      out[row0 + 2] = s2 + cc;
      out[row0 + 3] = s3 + cc;
    }
  }
}

extern "C" void kernel_launch(void* const* d_in, const int* in_sizes, int n_in,
                              void* d_out, int out_size, void* d_ws, size_t ws_size,
                              hipStream_t stream) {
  const float* node_features = (const float*)d_in[0];
  const float* w_n2l        = (const float*)d_in[1];
  const float* bias_n2l     = (const float*)d_in[2];
  const float* bias_picked  = (const float*)d_in[3];
  const float* conv_W       = (const float*)d_in[4];
  const float* conv_b       = (const float*)d_in[5];
  const float* lin1_W       = (const float*)d_in[6];
  const float* lin1_b       = (const float*)d_in[7];
  const float* lout_W       = (const float*)d_in[8];
  const float* lout_b       = (const float*)d_in[9];
  const int*   edges_src    = (const int*)d_in[11];
  const int*   edges_dst    = (const int*)d_in[12];
  const int*   target_nodes = (const int*)d_in[13];
  const int*   picked_nodes = (const int*)d_in[14];
  float* q_out = (float*)d_out;

  // workspace layout (deg+gsum adjacent -> single memset)
  float*  base = (float*)d_ws;                           // N*D fp32
  __half* b16  = (__half*)(base + (size_t)Nn * Dd);      // NR*D fp16 (relu'd)
  __half* b16p = b16 + (size_t)NR * Dd;                  // N*D fp16 (pre-relu)
  __half* hAh  = b16p + (size_t)Nn * Dd;                 // B*NR*D fp16
  __half* h2   = hAh + (size_t)Bg * NR * Dd;             // B*N*D fp16
  int*    deg  = (int*)(h2 + (size_t)Bg * Nn * Dd);      // B*N
  float*  gsum = (float*)(deg + (size_t)Bg * Nn);        // B*64
  int*    offs = (int*)(gsum + Bg * Dd);                 // B*N
  int*    ssrc = offs + (size_t)Bg * Nn;                 // B*E
  float*  cvec = (float*)(ssrc + (size_t)Bg * Eg);       // B*128
  float*  uvec = cvec + Bg * Hh;                         // B*128
  float*  csc  = uvec + Bg * Hh;                         // B

  hipMemsetAsync(deg, 0, ((size_t)Bg * Nn + Bg * Dd) * sizeof(int), stream);

  k_base<<<512, 256, 0, stream>>>(node_features, w_n2l, bias_n2l, base, b16, b16p);
  int eb = (Eg / 1024 + 1);  // 313 blocks/graph, 4 edges/thread
  k_hist<<<eb * Bg, 256, 0, stream>>>(edges_dst, deg);
  k_scan<<<Bg, 1024, 0, stream>>>(deg, offs, hAh);
  k_scatter<<<eb * Bg, 256, 0, stream>>>(edges_src, edges_dst, offs, ssrc);
  k_level<true><<<2048, 256, 0, stream>>>(b16, hAh, base, b16p, conv_W, conv_b,
                                          bias_picked, picked_nodes, deg, offs,
                                          ssrc, gsum);
  k_level<false><<<2048, 256, 0, stream>>>(hAh, h2, base, b16p, conv_W, conv_b,
                                           bias_picked, picked_nodes, deg, offs,
                                           ssrc, gsum);
  k_prep<<<Bg, 128, 0, stream>>>(h2, gsum, target_nodes, lin1_W, lin1_b, lout_W,
                                 lout_b, cvec, uvec, csc);
  k_final<<<2048, 256, 0, stream>>>(h2, lin1_W, cvec, uvec, csc, q_out);
}

// Round 9
// 540.251 us; speedup vs baseline: 1.9506x; 1.0172x over previous
//
#include <hip/hip_runtime.h>
#include <hip/hip_bf16.h>
#include <hip/hip_fp16.h>

#define Nn 20000
#define NR 20001   // rows incl. trailing dummy zero row (for pad gathers)
#define Bg 8
#define Eg 320000
#define FDim 128
#define Dd 64
#define Hh 128

typedef _Float16 v2h __attribute__((ext_vector_type(2)));
typedef unsigned short u16;

__device__ __forceinline__ float bcastf(float v, int l) {
  return __int_as_float(__builtin_amdgcn_readlane(__float_as_int(v), l));
}
__device__ __forceinline__ int bcasti(int v, int l) {
  return __builtin_amdgcn_readlane(v, l);
}
__device__ __forceinline__ v2h u2h2(unsigned u) { return __builtin_bit_cast(v2h, u); }
__device__ __forceinline__ unsigned h22u(__half2 h) { return __builtin_bit_cast(unsigned, h); }
__device__ __forceinline__ float fdot2f(v2h a, v2h b, float c) {
  return __builtin_amdgcn_fdot2(a, b, c, false);
}

// K1: base = x @ w_n2l + bias ; b16 = fp16(relu(base)) (gather source, row Nn = 0);
//     b16p = fp16(base) (epilogue stream)
__global__ __launch_bounds__(256) void k_base(const float* __restrict__ x,
                                              const float* __restrict__ W,
                                              const float* __restrict__ b,
                                              float* __restrict__ base,
                                              __half* __restrict__ b16,
                                              __half* __restrict__ b16p) {
  __shared__ float Wl[FDim * Dd];   // 32 KB
  int t = threadIdx.x;
  for (int i = t; i < FDim * Dd; i += 256) Wl[i] = W[i];
  __syncthreads();
  int wv = t >> 6, lane = t & 63;
  float bias = b[lane];
  for (int row = blockIdx.x * 4 + wv; row < NR; row += gridDim.x * 4) {
    if (row == Nn) {  // dummy zero row for pad gathers
      b16[(size_t)row * Dd + lane] = __float2half(0.f);
      continue;
    }
    float x0 = x[row * FDim + lane];
    float x1 = x[row * FDim + 64 + lane];
    float acc = bias;
#pragma unroll
    for (int k = 0; k < 64; ++k) acc = fmaf(bcastf(x0, k), Wl[k * Dd + lane], acc);
#pragma unroll
    for (int k = 0; k < 64; ++k) acc = fmaf(bcastf(x1, k), Wl[(64 + k) * Dd + lane], acc);
    base[row * Dd + lane] = acc;
    b16[row * Dd + lane] = __float2half(fmaxf(acc, 0.f));
    b16p[row * Dd + lane] = __float2half(acc);
  }
}

// K2: per-graph dst-degree histogram. Fully-RESIDENT XCD-affine grid:
// 2048 blocks (8/CU) all co-resident -> graph g's deg lines pinned to XCD g's L2.
__global__ __launch_bounds__(256) void k_hist(const int* __restrict__ dst,
                                              int* __restrict__ deg) {
  int g = blockIdx.x & 7;
  int lb = blockIdx.x >> 3;  // 0..255
  const int* dsrc = dst + (size_t)g * Eg;
  int* dp = deg + g * Nn;
  for (int e4 = (lb * 256 + threadIdx.x) * 4; e4 < Eg; e4 += 256 * 256 * 4) {
    int4 d4 = *(const int4*)(dsrc + e4);
    atomicAdd(&dp[d4.x], 1);
    atomicAdd(&dp[d4.y], 1);
    atomicAdd(&dp[d4.z], 1);
    atomicAdd(&dp[d4.w], 1);
  }
}

// K3: exclusive prefix-sum of deg -> offs (shfl-based). Zeroes dummy row of hA.
__global__ __launch_bounds__(1024) void k_scan(const int* __restrict__ deg,
                                               int* __restrict__ offs,
                                               __half* __restrict__ hA) {
  int g = blockIdx.x;
  if (threadIdx.x < Dd)
    hA[((size_t)g * NR + Nn) * Dd + threadIdx.x] = __float2half(0.f);
  const int* dp = deg + g * Nn;
  int* op = offs + g * Nn;
  __shared__ int wsum[16];
  __shared__ int carrysh;
  if (threadIdx.x == 0) carrysh = 0;
  int lane = threadIdx.x & 63, wv = threadIdx.x >> 6;
  __syncthreads();
  for (int b0 = 0; b0 < Nn; b0 += 4096) {
    int gidx = b0 + threadIdx.x * 4;
    int4 v = make_int4(0, 0, 0, 0);
    bool ok = (gidx + 3 < Nn);
    if (ok) v = *(const int4*)(dp + gidx);
    int s0 = v.x, s1 = s0 + v.y, s2 = s1 + v.z, s3 = s2 + v.w;
    int incl = s3;
#pragma unroll
    for (int off = 1; off < 64; off <<= 1) {
      int y = __shfl_up(incl, off, 64);
      if (lane >= off) incl += y;
    }
    if (lane == 63) wsum[wv] = incl;
    __syncthreads();
    if (threadIdx.x < 16) {
      int w = wsum[threadIdx.x];
      int wincl = w;
#pragma unroll
      for (int off = 1; off < 16; off <<= 1) {
        int y = __shfl_up(wincl, off, 64);
        if (lane >= off) wincl += y;
      }
      wsum[threadIdx.x] = wincl - w;  // exclusive wave offset
    }
    __syncthreads();
    int cc = carrysh;
    int woff = wsum[wv];
    int excl = cc + woff + incl - s3;
    if (ok) {
      int4 o;
      o.x = excl; o.y = excl + s0; o.z = excl + s1; o.w = excl + s2;
      *(int4*)(op + gidx) = o;
    }
    __syncthreads();
    if (threadIdx.x == 1023) carrysh = cc + woff + incl;
    __syncthreads();
  }
}

// K4: counting-sort scatter of src -> u16, resident XCD-affine grid
// (offs becomes END pointer after this).
__global__ __launch_bounds__(256) void k_scatter(const int* __restrict__ src,
                                                 const int* __restrict__ dst,
                                                 int* __restrict__ offs,
                                                 u16* __restrict__ ssrc) {
  int g = blockIdx.x & 7;
  int lb = blockIdx.x >> 3;  // 0..255
  const int* dsrc = dst + (size_t)g * Eg;
  const int* ssrcg = src + (size_t)g * Eg;
  int* op = offs + g * Nn;
  u16* sp = ssrc + (size_t)g * Eg;
  for (int e4 = (lb * 256 + threadIdx.x) * 4; e4 < Eg; e4 += 256 * 256 * 4) {
    int4 d4 = *(const int4*)(dsrc + e4);
    int4 s4 = *(const int4*)(ssrcg + e4);
    sp[atomicAdd(&op[d4.x], 1)] = (u16)s4.x;
    sp[atomicAdd(&op[d4.y], 1)] = (u16)s4.y;
    sp[atomicAdd(&op[d4.z], 1)] = (u16)s4.z;
    sp[atomicAdd(&op[d4.w], 1)] = (u16)s4.w;
  }
}

// K5: fused SpMM + conv matvec (v_dot2_f32_f16, conv_W packed in 32 pinned
// VGPRs) + relu. Row PAIR per wave; ballot-based pick counting in LV1.
template <bool LV1>
__global__ __launch_bounds__(256, 4) void k_level(
    const __half* __restrict__ gsrc,   // LV1: b16 (NR rows); LV2: hA (B*NR rows)
    __half* __restrict__ hout,         // LV1: hA (NR stride); LV2: h2 (Nn stride)
    const float* __restrict__ base,
    const __half* __restrict__ b16p,
    const float* __restrict__ convW, const float* __restrict__ convb,
    const float* __restrict__ biasp, const int* __restrict__ picked,
    const int* __restrict__ deg, const int* __restrict__ offs,
    const u16* __restrict__ ssrc, float* __restrict__ gsum) {
  int t = threadIdx.x;
  int wv = t >> 6, lane = t & 63;
  // conv_W column `lane`, packed (d,d+1) pairs -> 32 VGPRs, pinned vs remat
  unsigned wc[32];
#pragma unroll
  for (int d2 = 0; d2 < 32; ++d2)
    wc[d2] = h22u(__floats2half2_rn(convW[(2 * d2) * Dd + lane],
                                    (convW[(2 * d2 + 1) * Dd + lane])));
#pragma unroll
  for (int d2 = 0; d2 < 32; ++d2) asm volatile("" : "+v"(wc[d2]));
  float cb = convb[lane];
  float bp = biasp[lane];
  int g = blockIdx.x & 7;
  int lb = blockIdx.x >> 3;
  int pstride = (gridDim.x >> 3) * 4;
  int pick = picked[g];
  int gN = g * Nn;
  const u16* sp = ssrc + (size_t)g * Eg;
  const __half* hsrc = LV1 ? gsrc : (gsrc + (size_t)g * NR * Dd);
  __half* outp = LV1 ? (hout + (size_t)g * NR * Dd) : (hout + (size_t)g * Nn * Dd);
  float delta = 0.f;
  if (LV1) {
    float db = base[(size_t)pick * Dd + lane];
    float d16 = __half2float(__float2half(fmaxf(db, 0.f)));
    delta = fmaxf(db + bp, 0.f) - d16;  // true pick row minus stored b16 row
  }
  float gs = 0.f;

  for (int p = lb * 4 + wv; p < Nn / 2; p += pstride) {
    int i0 = p * 2, i1 = i0 + 1;
    int2 dg2 = *(const int2*)&deg[gN + i0];
    int d0 = dg2.x, dtot = d0 + dg2.y;
    int end0 = offs[gN + i0];
    int beg0 = end0 - d0;

    float a0 = 0.f, aT = 0.f;
    if (dtot <= 64) {
      int svm = Nn;  // dummy (zero row) for pad lanes
      if (lane < dtot) svm = (int)sp[beg0 + lane];  // one coalesced u16 load
      if (LV1) {
        unsigned long long pm = __ballot(svm == pick);
        unsigned long long m0 = (d0 >= 64) ? ~0ull : ((1ull << d0) - 1ull);
        a0 += (float)__popcll(pm & m0) * delta;
        aT += (float)__popcll(pm) * delta;
      }
      int nch = (dtot + 7) >> 3;
      for (int c = 0; c < nch; ++c) {
        int j = c * 8;
        int s0 = bcasti(svm, j + 0), s1 = bcasti(svm, j + 1);
        int s2 = bcasti(svm, j + 2), s3 = bcasti(svm, j + 3);
        int s4 = bcasti(svm, j + 4), s5 = bcasti(svm, j + 5);
        int s6 = bcasti(svm, j + 6), s7 = bcasti(svm, j + 7);
        float v0 = __half2float(hsrc[((unsigned)s0 << 6) + lane]);
        float v1 = __half2float(hsrc[((unsigned)s1 << 6) + lane]);
        float v2 = __half2float(hsrc[((unsigned)s2 << 6) + lane]);
        float v3 = __half2float(hsrc[((unsigned)s3 << 6) + lane]);
        float v4 = __half2float(hsrc[((unsigned)s4 << 6) + lane]);
        float v5 = __half2float(hsrc[((unsigned)s5 << 6) + lane]);
        float v6 = __half2float(hsrc[((unsigned)s6 << 6) + lane]);
        float v7 = __half2float(hsrc[((unsigned)s7 << 6) + lane]);
        float cs = ((v0 + v1) + (v2 + v3)) + ((v4 + v5) + (v6 + v7));
        aT += cs;  // pads contribute exactly 0 (dummy zero row)
        if (j + 8 <= d0) {
          a0 += cs;
        } else if (j < d0) {  // the single row0/row1 boundary chunk
          int r = d0 - j;  // 1..7
          float pfx = (r > 0 ? v0 : 0.f) + (r > 1 ? v1 : 0.f) + (r > 2 ? v2 : 0.f) +
                      (r > 3 ? v3 : 0.f) + (r > 4 ? v4 : 0.f) + (r > 5 ? v5 : 0.f) +
                      (r > 6 ? v6 : 0.f);
          a0 += pfx;
        }
      }
    } else {  // rare fallback: serial per-edge
      int c0cnt = 0, cTcnt = 0;
      for (int e = beg0; e < end0; ++e) {
        int s = (int)sp[e];
        if (LV1) c0cnt += (s == pick);
        a0 += __half2float(hsrc[((unsigned)s << 6) + lane]);
      }
      aT = a0;
      int end1 = beg0 + dtot;
      for (int e = end0; e < end1; ++e) {
        int s = (int)sp[e];
        if (LV1) cTcnt += (s == pick);
        aT += __half2float(hsrc[((unsigned)s << 6) + lane]);
      }
      if (LV1) {
        a0 += (float)c0cnt * delta;
        aT += (float)(cTcnt + c0cnt) * delta;
      }
    }
    float a1 = aT - a0;
    float acc0 = a0 * (d0 ? 1.0f / (float)d0 : 0.f);
    float acc1 = a1 * (dg2.y ? 1.0f / (float)dg2.y : 0.f);

    // pack (acc[2k], acc[2k+1]) into lane k's half2 -> readlane broadcasts pairs
    unsigned p0 = h22u(__floats2half2_rn(acc0, __shfl_down(acc0, 1, 64)));
    unsigned p1 = h22u(__floats2half2_rn(acc1, __shfl_down(acc1, 1, 64)));

    float o0a = __half2float(b16p[(size_t)i0 * Dd + lane]) + cb, o0b = 0.f;
    float o1a = __half2float(b16p[(size_t)i1 * Dd + lane]) + cb, o1b = 0.f;
    if (i0 == pick) o0a += bp;
    if (i1 == pick) o1a += bp;
#pragma unroll
    for (int d2 = 0; d2 < 32; d2 += 2) {
      v2h m00 = u2h2(bcasti(p0, 2 * d2)),     m01 = u2h2(bcasti(p0, 2 * d2 + 2));
      v2h m10 = u2h2(bcasti(p1, 2 * d2)),     m11 = u2h2(bcasti(p1, 2 * d2 + 2));
      o0a = fdot2f(m00, u2h2(wc[d2]), o0a);
      o0b = fdot2f(m01, u2h2(wc[d2 + 1]), o0b);
      o1a = fdot2f(m10, u2h2(wc[d2]), o1a);
      o1b = fdot2f(m11, u2h2(wc[d2 + 1]), o1b);
    }
    float out0 = fmaxf(o0a + o0b, 0.f);
    float out1 = fmaxf(o1a + o1b, 0.f);
    outp[(size_t)i0 * Dd + lane] = __float2half(out0);
    outp[(size_t)i1 * Dd + lane] = __float2half(out1);
    if (!LV1) gs += out0 + out1;
  }
  if (!LV1) atomicAdd(&gsum[g * Dd + lane], gs);
}

// K7: per-graph constants: cvec = g_embed@lin1_W[64:] + lin1_b ; u = lout_W@t ; c = lout_b.t
__global__ __launch_bounds__(128) void k_prep(
    const __half* __restrict__ h2, const float* __restrict__ gsum,
    const int* __restrict__ tgt, const float* __restrict__ lin1W,
    const float* __restrict__ lin1b, const float* __restrict__ loutW,
    const float* __restrict__ loutb, float* __restrict__ cvec,
    float* __restrict__ uvec, float* __restrict__ cscal) {
  int g = blockIdx.x;
  int k = threadIdx.x;
  __shared__ float tv[Dd], ge[Dd];
  if (k < Dd) {
    tv[k] = __half2float(h2[(size_t)g * Nn * Dd + (size_t)tgt[g] * Dd + k]);
    ge[k] = gsum[g * Dd + k] * (1.0f / Nn);
  }
  __syncthreads();
  float cv = lin1b[k];
#pragma unroll 8
  for (int d = 0; d < Dd; ++d) cv = fmaf(ge[d], lin1W[(Dd + d) * Hh + k], cv);
  cvec[g * Hh + k] = cv;
  float uu = 0.f;
#pragma unroll 8
  for (int j = 0; j < Dd; ++j) uu = fmaf(loutW[k * Dd + j], tv[j], uu);
  uvec[g * Hh + k] = uu;
  if (k == 0) {
    float c = 0.f;
    for (int j = 0; j < Dd; ++j) c += loutb[j] * tv[j];
    cscal[g] = c;
  }
}

// K8: q[g,i] = sum_k relu(h_i . W1[:,k] + cvec[k]) * u[k] + c
// 4 rows/wave, fp16 h2 + half2 LDS W1 + v_dot2_f32_f16.
__global__ __launch_bounds__(256) void k_final(
    const __half* __restrict__ h2, const float* __restrict__ lin1W,
    const float* __restrict__ cvec, const float* __restrict__ uvec,
    const float* __restrict__ cscal, float* __restrict__ out) {
  __shared__ unsigned Wl2[32 * Hh];  // 16 KB: (W1[2d2][c], W1[2d2+1][c]) pairs
  int t = threadIdx.x;
  for (int i = t; i < 32 * Hh; i += 256) {
    int d2 = i >> 7, c = i & 127;
    Wl2[i] = h22u(__floats2half2_rn(lin1W[(2 * d2) * Hh + c],
                                    lin1W[(2 * d2 + 1) * Hh + c]));
  }
  __syncthreads();
  int wv = t >> 6, lane = t & 63;
  int lr = lane & 31, hi = lane >> 5;
  int tot = Bg * Nn / 4;
  for (int p = blockIdx.x * 4 + wv; p < tot; p += gridDim.x * 4) {
    int row0 = p * 4;
    int g = row0 / Nn;
    int i0 = row0 - g * Nn;
    const __half2* hb = (const __half2*)(h2 + (size_t)g * Nn * Dd);
    // ra: rows i0 (lanes 0-31) / i0+1 (lanes 32-63); rb: i0+2 / i0+3
    unsigned ra = h22u(hb[(size_t)(i0 + hi) * 32 + lr]);
    unsigned rb = h22u(hb[(size_t)(i0 + 2 + hi) * 32 + lr]);
    float c0 = cvec[g * Hh + lane], c1 = cvec[g * Hh + 64 + lane];
    float u0 = uvec[g * Hh + lane], u1 = uvec[g * Hh + 64 + lane];
    float za0 = c0, za1 = c1, zb0 = c0, zb1 = c1;
    float zc0 = c0, zc1 = c1, zd0 = c0, zd1 = c1;
#pragma unroll
    for (int d2 = 0; d2 < 32; ++d2) {
      v2h w0 = u2h2(Wl2[d2 * Hh + lane]);
      v2h w1 = u2h2(Wl2[d2 * Hh + 64 + lane]);
      v2h a0 = u2h2(bcasti(ra, d2)), a1 = u2h2(bcasti(ra, 32 + d2));
      v2h b0 = u2h2(bcasti(rb, d2)), b1 = u2h2(bcasti(rb, 32 + d2));
      za0 = fdot2f(a0, w0, za0);  za1 = fdot2f(a0, w1, za1);
      zb0 = fdot2f(a1, w0, zb0);  zb1 = fdot2f(a1, w1, zb1);
      zc0 = fdot2f(b0, w0, zc0);  zc1 = fdot2f(b0, w1, zc1);
      zd0 = fdot2f(b1, w0, zd0);  zd1 = fdot2f(b1, w1, zd1);
    }
    float s0 = fmaxf(za0, 0.f) * u0 + fmaxf(za1, 0.f) * u1;
    float s1 = fmaxf(zb0, 0.f) * u0 + fmaxf(zb1, 0.f) * u1;
    float s2 = fmaxf(zc0, 0.f) * u0 + fmaxf(zc1, 0.f) * u1;
    float s3 = fmaxf(zd0, 0.f) * u0 + fmaxf(zd1, 0.f) * u1;
#pragma unroll
    for (int off = 32; off; off >>= 1) {
      s0 += __shfl_xor(s0, off, 64);
      s1 += __shfl_xor(s1, off, 64);
      s2 += __shfl_xor(s2, off, 64);
      s3 += __shfl_xor(s3, off, 64);
    }
    if (lane == 0) {
      float cc = cscal[g];
      out[row0] = s0 + cc;
      out[row0 + 1] = s1 + cc;
      out[row0 + 2] = s2 + cc;
      out[row0 + 3] = s3 + cc;
    }
  }
}

extern "C" void kernel_launch(void* const* d_in, const int* in_sizes, int n_in,
                              void* d_out, int out_size, void* d_ws, size_t ws_size,
                              hipStream_t stream) {
  const float* node_features = (const float*)d_in[0];
  const float* w_n2l        = (const float*)d_in[1];
  const float* bias_n2l     = (const float*)d_in[2];
  const float* bias_picked  = (const float*)d_in[3];
  const float* conv_W       = (const float*)d_in[4];
  const float* conv_b       = (const float*)d_in[5];
  const float* lin1_W       = (const float*)d_in[6];
  const float* lin1_b       = (const float*)d_in[7];
  const float* lout_W       = (const float*)d_in[8];
  const float* lout_b       = (const float*)d_in[9];
  const int*   edges_src    = (const int*)d_in[11];
  const int*   edges_dst    = (const int*)d_in[12];
  const int*   target_nodes = (const int*)d_in[13];
  const int*   picked_nodes = (const int*)d_in[14];
  float* q_out = (float*)d_out;

  // workspace layout (deg+gsum adjacent -> single memset)
  float*  base = (float*)d_ws;                           // N*D fp32
  __half* b16  = (__half*)(base + (size_t)Nn * Dd);      // NR*D fp16 (relu'd)
  __half* b16p = b16 + (size_t)NR * Dd;                  // N*D fp16 (pre-relu)
  __half* hAh  = b16p + (size_t)Nn * Dd;                 // B*NR*D fp16
  __half* h2   = hAh + (size_t)Bg * NR * Dd;             // B*N*D fp16
  int*    deg  = (int*)(h2 + (size_t)Bg * Nn * Dd);      // B*N
  float*  gsum = (float*)(deg + (size_t)Bg * Nn);        // B*64
  int*    offs = (int*)(gsum + Bg * Dd);                 // B*N
  u16*    ssrc = (u16*)(offs + (size_t)Bg * Nn);         // B*E u16
  float*  cvec = (float*)(ssrc + (size_t)Bg * Eg);       // B*128
  float*  uvec = cvec + Bg * Hh;                         // B*128
  float*  csc  = uvec + Bg * Hh;                         // B

  hipMemsetAsync(deg, 0, ((size_t)Bg * Nn + Bg * Dd) * sizeof(int), stream);

  k_base<<<512, 256, 0, stream>>>(node_features, w_n2l, bias_n2l, base, b16, b16p);
  k_hist<<<2048, 256, 0, stream>>>(edges_dst, deg);
  k_scan<<<Bg, 1024, 0, stream>>>(deg, offs, hAh);
  k_scatter<<<2048, 256, 0, stream>>>(edges_src, edges_dst, offs, ssrc);
  k_level<true><<<2048, 256, 0, stream>>>(b16, hAh, base, b16p, conv_W, conv_b,
                                          bias_picked, picked_nodes, deg, offs,
                                          ssrc, gsum);
  k_level<false><<<2048, 256, 0, stream>>>(hAh, h2, base, b16p, conv_W, conv_b,
                                           bias_picked, picked_nodes, deg, offs,
                                           ssrc, gsum);
  k_prep<<<Bg, 128, 0, stream>>>(h2, gsum, target_nodes, lin1_W, lin1_b, lout_W,
                                 lout_b, cvec, uvec, csc);
  k_final<<<2048, 256, 0, stream>>>(h2, lin1_W, cvec, uvec, csc, q_out);
}

// Round 10
// 406.805 us; speedup vs baseline: 2.5904x; 1.3280x over previous
//
#include <hip/hip_runtime.h>
#include <hip/hip_bf16.h>
#include <hip/hip_fp16.h>

#define Nn 20000
#define NR 20001   // rows incl. trailing dummy zero row (for pad gathers)
#define Bg 8
#define Eg 320000
#define FDim 128
#define Dd 64
#define Hh 128
#define NCH 16               // edge chunks per graph
#define CHE (Eg / NCH)       // 20000 edges per chunk

typedef _Float16 v2h __attribute__((ext_vector_type(2)));
typedef unsigned short u16;

__device__ __forceinline__ float bcastf(float v, int l) {
  return __int_as_float(__builtin_amdgcn_readlane(__float_as_int(v), l));
}
__device__ __forceinline__ int bcasti(int v, int l) {
  return __builtin_amdgcn_readlane(v, l);
}
__device__ __forceinline__ v2h u2h2(unsigned u) { return __builtin_bit_cast(v2h, u); }
__device__ __forceinline__ unsigned h22u(__half2 h) { return __builtin_bit_cast(unsigned, h); }
__device__ __forceinline__ float fdot2f(v2h a, v2h b, float c) {
  return __builtin_amdgcn_fdot2(a, b, c, false);
}

// K1: base = x @ w_n2l + bias ; b16 = fp16(relu(base)) (gather source, row Nn = 0);
//     b16p = fp16(base) (epilogue stream)
__global__ __launch_bounds__(256) void k_base(const float* __restrict__ x,
                                              const float* __restrict__ W,
                                              const float* __restrict__ b,
                                              float* __restrict__ base,
                                              __half* __restrict__ b16,
                                              __half* __restrict__ b16p) {
  __shared__ float Wl[FDim * Dd];   // 32 KB
  int t = threadIdx.x;
  for (int i = t; i < FDim * Dd; i += 256) Wl[i] = W[i];
  __syncthreads();
  int wv = t >> 6, lane = t & 63;
  float bias = b[lane];
  for (int row = blockIdx.x * 4 + wv; row < NR; row += gridDim.x * 4) {
    if (row == Nn) {  // dummy zero row for pad gathers
      b16[(size_t)row * Dd + lane] = __float2half(0.f);
      continue;
    }
    float x0 = x[row * FDim + lane];
    float x1 = x[row * FDim + 64 + lane];
    float acc = bias;
#pragma unroll
    for (int k = 0; k < 64; ++k) acc = fmaf(bcastf(x0, k), Wl[k * Dd + lane], acc);
#pragma unroll
    for (int k = 0; k < 64; ++k) acc = fmaf(bcastf(x1, k), Wl[(64 + k) * Dd + lane], acc);
    base[row * Dd + lane] = acc;
    b16[row * Dd + lane] = __float2half(fmaxf(acc, 0.f));
    b16p[row * Dd + lane] = __float2half(acc);
  }
}

// K2: per-chunk histogram in PRIVATE LDS (no global atomics -> no memory-side
// RMW traffic). 128 blocks = 16 chunks x 8 graphs, XCD-affine (g = blk&7).
__global__ __launch_bounds__(1024) void k_hist(const int* __restrict__ dst,
                                               int* __restrict__ hpart) {
  __shared__ int lh[Nn];  // 80 KB
  int g = blockIdx.x & 7;
  int c = blockIdx.x >> 3;
  for (int i = threadIdx.x; i < Nn; i += 1024) lh[i] = 0;
  __syncthreads();
  const int* dp = dst + (size_t)g * Eg + c * CHE;
  for (int e4 = threadIdx.x * 4; e4 < CHE; e4 += 4096) {
    int4 d4 = *(const int4*)(dp + e4);
    atomicAdd(&lh[d4.x], 1);
    atomicAdd(&lh[d4.y], 1);
    atomicAdd(&lh[d4.z], 1);
    atomicAdd(&lh[d4.w], 1);
  }
  __syncthreads();
  int* out = hpart + (size_t)(g * NCH + c) * Nn;
  for (int i = threadIdx.x; i < Nn; i += 1024) out[i] = lh[i];
}

// K3: per graph: deg = sum partials; offs = exclusive scan(deg);
// hpart[c] <- scatter base (offs + running partial prefix), in place.
// Also zeroes the per-graph dummy row of hA.
__global__ __launch_bounds__(1024) void k_scan(int* __restrict__ hpart,
                                               int* __restrict__ deg,
                                               int* __restrict__ offs,
                                               __half* __restrict__ hA) {
  int g = blockIdx.x;
  if (threadIdx.x < Dd)
    hA[((size_t)g * NR + Nn) * Dd + threadIdx.x] = __float2half(0.f);
  int* hp = hpart + (size_t)g * NCH * Nn;
  int* dp = deg + g * Nn;
  int* op = offs + g * Nn;
  __shared__ int wsum[16];
  __shared__ int carrysh;
  if (threadIdx.x == 0) carrysh = 0;
  int lane = threadIdx.x & 63, wv = threadIdx.x >> 6;
  __syncthreads();
  for (int b0 = 0; b0 < Nn; b0 += 4096) {
    int gidx = b0 + threadIdx.x * 4;
    bool ok = (gidx < Nn);  // Nn % 4 == 0
    int4 s = make_int4(0, 0, 0, 0);
    if (ok) {
#pragma unroll
      for (int c = 0; c < NCH; ++c) {
        int4 v = *(const int4*)(hp + (size_t)c * Nn + gidx);
        s.x += v.x; s.y += v.y; s.z += v.z; s.w += v.w;
      }
      *(int4*)(dp + gidx) = s;
    }
    int s0 = s.x, s1 = s0 + s.y, s2 = s1 + s.z, s3 = s2 + s.w;
    int incl = s3;
#pragma unroll
    for (int off = 1; off < 64; off <<= 1) {
      int y = __shfl_up(incl, off, 64);
      if (lane >= off) incl += y;
    }
    if (lane == 63) wsum[wv] = incl;
    __syncthreads();
    if (threadIdx.x < 16) {
      int w = wsum[threadIdx.x];
      int wincl = w;
#pragma unroll
      for (int off = 1; off < 16; off <<= 1) {
        int y = __shfl_up(wincl, off, 64);
        if (lane >= off) wincl += y;
      }
      wsum[threadIdx.x] = wincl - w;  // exclusive wave offset
    }
    __syncthreads();
    int cc = carrysh;
    int excl = cc + wsum[wv] + incl - s3;
    if (ok) {
      int4 o;
      o.x = excl; o.y = excl + s0; o.z = excl + s1; o.w = excl + s2;
      *(int4*)(op + gidx) = o;
      // pass B: per-chunk scatter bases (in-place over hpart)
      int4 run = o;
#pragma unroll
      for (int c = 0; c < NCH; ++c) {
        int4 v = *(const int4*)(hp + (size_t)c * Nn + gidx);
        *(int4*)(hp + (size_t)c * Nn + gidx) = run;
        run.x += v.x; run.y += v.y; run.z += v.z; run.w += v.w;
      }
    }
    __syncthreads();
    if (threadIdx.x == 1023) carrysh = cc + wsum[15] + __shfl(incl, 63, 64);
    __syncthreads();
  }
}

// K4: scatter via LDS rank counters + precomputed per-chunk bases.
// Plain u16 stores, ZERO global atomics.
__global__ __launch_bounds__(1024) void k_scatter(const int* __restrict__ src,
                                                  const int* __restrict__ dst,
                                                  const int* __restrict__ basep,
                                                  u16* __restrict__ ssrc) {
  __shared__ int lc[Nn];  // 80 KB rank counters
  int g = blockIdx.x & 7;
  int c = blockIdx.x >> 3;
  for (int i = threadIdx.x; i < Nn; i += 1024) lc[i] = 0;
  __syncthreads();
  const int* dp = dst + (size_t)g * Eg + c * CHE;
  const int* sp_in = src + (size_t)g * Eg + c * CHE;
  const int* bp = basep + (size_t)(g * NCH + c) * Nn;
  u16* out = ssrc + (size_t)g * Eg;
  for (int e4 = threadIdx.x * 4; e4 < CHE; e4 += 4096) {
    int4 d4 = *(const int4*)(dp + e4);
    int4 s4 = *(const int4*)(sp_in + e4);
    int r0 = atomicAdd(&lc[d4.x], 1); out[bp[d4.x] + r0] = (u16)s4.x;
    int r1 = atomicAdd(&lc[d4.y], 1); out[bp[d4.y] + r1] = (u16)s4.y;
    int r2 = atomicAdd(&lc[d4.z], 1); out[bp[d4.z] + r2] = (u16)s4.z;
    int r3 = atomicAdd(&lc[d4.w], 1); out[bp[d4.w] + r3] = (u16)s4.w;
  }
}

// K5: fused SpMM + conv matvec (v_dot2_f32_f16, conv_W packed in 32 pinned
// VGPRs) + relu. Row PAIR per wave; ballot-based pick counting in LV1.
// offs is a START pointer now (scatter no longer mutates it).
template <bool LV1>
__global__ __launch_bounds__(256, 4) void k_level(
    const __half* __restrict__ gsrc,   // LV1: b16 (NR rows); LV2: hA (B*NR rows)
    __half* __restrict__ hout,         // LV1: hA (NR stride); LV2: h2 (Nn stride)
    const float* __restrict__ base,
    const __half* __restrict__ b16p,
    const float* __restrict__ convW, const float* __restrict__ convb,
    const float* __restrict__ biasp, const int* __restrict__ picked,
    const int* __restrict__ deg, const int* __restrict__ offs,
    const u16* __restrict__ ssrc, float* __restrict__ gsum) {
  int t = threadIdx.x;
  int wv = t >> 6, lane = t & 63;
  // conv_W column `lane`, packed (d,d+1) pairs -> 32 VGPRs, pinned vs remat
  unsigned wc[32];
#pragma unroll
  for (int d2 = 0; d2 < 32; ++d2)
    wc[d2] = h22u(__floats2half2_rn(convW[(2 * d2) * Dd + lane],
                                    (convW[(2 * d2 + 1) * Dd + lane])));
#pragma unroll
  for (int d2 = 0; d2 < 32; ++d2) asm volatile("" : "+v"(wc[d2]));
  float cb = convb[lane];
  float bp = biasp[lane];
  int g = blockIdx.x & 7;
  int lb = blockIdx.x >> 3;
  int pstride = (gridDim.x >> 3) * 4;
  int pick = picked[g];
  int gN = g * Nn;
  const u16* sp = ssrc + (size_t)g * Eg;
  const __half* hsrc = LV1 ? gsrc : (gsrc + (size_t)g * NR * Dd);
  __half* outp = LV1 ? (hout + (size_t)g * NR * Dd) : (hout + (size_t)g * Nn * Dd);
  float delta = 0.f;
  if (LV1) {
    float db = base[(size_t)pick * Dd + lane];
    float d16 = __half2float(__float2half(fmaxf(db, 0.f)));
    delta = fmaxf(db + bp, 0.f) - d16;  // true pick row minus stored b16 row
  }
  float gs = 0.f;

  for (int p = lb * 4 + wv; p < Nn / 2; p += pstride) {
    int i0 = p * 2, i1 = i0 + 1;
    int2 dg2 = *(const int2*)&deg[gN + i0];
    int d0 = dg2.x, dtot = d0 + dg2.y;
    int beg0 = offs[gN + i0];

    float a0 = 0.f, aT = 0.f;
    if (dtot <= 64) {
      int svm = Nn;  // dummy (zero row) for pad lanes
      if (lane < dtot) svm = (int)sp[beg0 + lane];  // one coalesced u16 load
      if (LV1) {
        unsigned long long pm = __ballot(svm == pick);
        unsigned long long m0 = (d0 >= 64) ? ~0ull : ((1ull << d0) - 1ull);
        a0 += (float)__popcll(pm & m0) * delta;
        aT += (float)__popcll(pm) * delta;
      }
      int nch = (dtot + 7) >> 3;
      for (int c = 0; c < nch; ++c) {
        int j = c * 8;
        int s0 = bcasti(svm, j + 0), s1 = bcasti(svm, j + 1);
        int s2 = bcasti(svm, j + 2), s3 = bcasti(svm, j + 3);
        int s4 = bcasti(svm, j + 4), s5 = bcasti(svm, j + 5);
        int s6 = bcasti(svm, j + 6), s7 = bcasti(svm, j + 7);
        float v0 = __half2float(hsrc[((unsigned)s0 << 6) + lane]);
        float v1 = __half2float(hsrc[((unsigned)s1 << 6) + lane]);
        float v2 = __half2float(hsrc[((unsigned)s2 << 6) + lane]);
        float v3 = __half2float(hsrc[((unsigned)s3 << 6) + lane]);
        float v4 = __half2float(hsrc[((unsigned)s4 << 6) + lane]);
        float v5 = __half2float(hsrc[((unsigned)s5 << 6) + lane]);
        float v6 = __half2float(hsrc[((unsigned)s6 << 6) + lane]);
        float v7 = __half2float(hsrc[((unsigned)s7 << 6) + lane]);
        float cs = ((v0 + v1) + (v2 + v3)) + ((v4 + v5) + (v6 + v7));
        aT += cs;  // pads contribute exactly 0 (dummy zero row)
        if (j + 8 <= d0) {
          a0 += cs;
        } else if (j < d0) {  // the single row0/row1 boundary chunk
          int r = d0 - j;  // 1..7
          float pfx = (r > 0 ? v0 : 0.f) + (r > 1 ? v1 : 0.f) + (r > 2 ? v2 : 0.f) +
                      (r > 3 ? v3 : 0.f) + (r > 4 ? v4 : 0.f) + (r > 5 ? v5 : 0.f) +
                      (r > 6 ? v6 : 0.f);
          a0 += pfx;
        }
      }
    } else {  // rare fallback: serial per-edge
      int c0cnt = 0, cTcnt = 0;
      int end0 = beg0 + d0, end1 = beg0 + dtot;
      for (int e = beg0; e < end0; ++e) {
        int s = (int)sp[e];
        if (LV1) c0cnt += (s == pick);
        a0 += __half2float(hsrc[((unsigned)s << 6) + lane]);
      }
      aT = a0;
      for (int e = end0; e < end1; ++e) {
        int s = (int)sp[e];
        if (LV1) cTcnt += (s == pick);
        aT += __half2float(hsrc[((unsigned)s << 6) + lane]);
      }
      if (LV1) {
        a0 += (float)c0cnt * delta;
        aT += (float)(cTcnt + c0cnt) * delta;
      }
    }
    float a1 = aT - a0;
    float acc0 = a0 * (d0 ? 1.0f / (float)d0 : 0.f);
    float acc1 = a1 * (dg2.y ? 1.0f / (float)dg2.y : 0.f);

    // pack (acc[2k], acc[2k+1]) into lane k's half2 -> readlane broadcasts pairs
    unsigned p0 = h22u(__floats2half2_rn(acc0, __shfl_down(acc0, 1, 64)));
    unsigned p1 = h22u(__floats2half2_rn(acc1, __shfl_down(acc1, 1, 64)));

    float o0a = __half2float(b16p[(size_t)i0 * Dd + lane]) + cb, o0b = 0.f;
    float o1a = __half2float(b16p[(size_t)i1 * Dd + lane]) + cb, o1b = 0.f;
    if (i0 == pick) o0a += bp;
    if (i1 == pick) o1a += bp;
#pragma unroll
    for (int d2 = 0; d2 < 32; d2 += 2) {
      v2h m00 = u2h2(bcasti(p0, 2 * d2)),     m01 = u2h2(bcasti(p0, 2 * d2 + 2));
      v2h m10 = u2h2(bcasti(p1, 2 * d2)),     m11 = u2h2(bcasti(p1, 2 * d2 + 2));
      o0a = fdot2f(m00, u2h2(wc[d2]), o0a);
      o0b = fdot2f(m01, u2h2(wc[d2 + 1]), o0b);
      o1a = fdot2f(m10, u2h2(wc[d2]), o1a);
      o1b = fdot2f(m11, u2h2(wc[d2 + 1]), o1b);
    }
    float out0 = fmaxf(o0a + o0b, 0.f);
    float out1 = fmaxf(o1a + o1b, 0.f);
    outp[(size_t)i0 * Dd + lane] = __float2half(out0);
    outp[(size_t)i1 * Dd + lane] = __float2half(out1);
    if (!LV1) gs += out0 + out1;
  }
  if (!LV1) atomicAdd(&gsum[g * Dd + lane], gs);
}

// K7: per-graph constants: cvec = g_embed@lin1_W[64:] + lin1_b ; u = lout_W@t ; c = lout_b.t
__global__ __launch_bounds__(128) void k_prep(
    const __half* __restrict__ h2, const float* __restrict__ gsum,
    const int* __restrict__ tgt, const float* __restrict__ lin1W,
    const float* __restrict__ lin1b, const float* __restrict__ loutW,
    const float* __restrict__ loutb, float* __restrict__ cvec,
    float* __restrict__ uvec, float* __restrict__ cscal) {
  int g = blockIdx.x;
  int k = threadIdx.x;
  __shared__ float tv[Dd], ge[Dd];
  if (k < Dd) {
    tv[k] = __half2float(h2[(size_t)g * Nn * Dd + (size_t)tgt[g] * Dd + k]);
    ge[k] = gsum[g * Dd + k] * (1.0f / Nn);
  }
  __syncthreads();
  float cv = lin1b[k];
#pragma unroll 8
  for (int d = 0; d < Dd; ++d) cv = fmaf(ge[d], lin1W[(Dd + d) * Hh + k], cv);
  cvec[g * Hh + k] = cv;
  float uu = 0.f;
#pragma unroll 8
  for (int j = 0; j < Dd; ++j) uu = fmaf(loutW[k * Dd + j], tv[j], uu);
  uvec[g * Hh + k] = uu;
  if (k == 0) {
    float c = 0.f;
    for (int j = 0; j < Dd; ++j) c += loutb[j] * tv[j];
    cscal[g] = c;
  }
}

// K8: q[g,i] = sum_k relu(h_i . W1[:,k] + cvec[k]) * u[k] + c
// 4 rows/wave, fp16 h2 + half2 LDS W1 + v_dot2_f32_f16.
__global__ __launch_bounds__(256) void k_final(
    const __half* __restrict__ h2, const float* __restrict__ lin1W,
    const float* __restrict__ cvec, const float* __restrict__ uvec,
    const float* __restrict__ cscal, float* __restrict__ out) {
  __shared__ unsigned Wl2[32 * Hh];  // 16 KB: (W1[2d2][c], W1[2d2+1][c]) pairs
  int t = threadIdx.x;
  for (int i = t; i < 32 * Hh; i += 256) {
    int d2 = i >> 7, c = i & 127;
    Wl2[i] = h22u(__floats2half2_rn(lin1W[(2 * d2) * Hh + c],
                                    lin1W[(2 * d2 + 1) * Hh + c]));
  }
  __syncthreads();
  int wv = t >> 6, lane = t & 63;
  int lr = lane & 31, hi = lane >> 5;
  int tot = Bg * Nn / 4;
  for (int p = blockIdx.x * 4 + wv; p < tot; p += gridDim.x * 4) {
    int row0 = p * 4;
    int g = row0 / Nn;
    int i0 = row0 - g * Nn;
    const __half2* hb = (const __half2*)(h2 + (size_t)g * Nn * Dd);
    // ra: rows i0 (lanes 0-31) / i0+1 (lanes 32-63); rb: i0+2 / i0+3
    unsigned ra = h22u(hb[(size_t)(i0 + hi) * 32 + lr]);
    unsigned rb = h22u(hb[(size_t)(i0 + 2 + hi) * 32 + lr]);
    float c0 = cvec[g * Hh + lane], c1 = cvec[g * Hh + 64 + lane];
    float u0 = uvec[g * Hh + lane], u1 = uvec[g * Hh + 64 + lane];
    float za0 = c0, za1 = c1, zb0 = c0, zb1 = c1;
    float zc0 = c0, zc1 = c1, zd0 = c0, zd1 = c1;
#pragma unroll
    for (int d2 = 0; d2 < 32; ++d2) {
      v2h w0 = u2h2(Wl2[d2 * Hh + lane]);
      v2h w1 = u2h2(Wl2[d2 * Hh + 64 + lane]);
      v2h a0 = u2h2(bcasti(ra, d2)), a1 = u2h2(bcasti(ra, 32 + d2));
      v2h b0 = u2h2(bcasti(rb, d2)), b1 = u2h2(bcasti(rb, 32 + d2));
      za0 = fdot2f(a0, w0, za0);  za1 = fdot2f(a0, w1, za1);
      zb0 = fdot2f(a1, w0, zb0);  zb1 = fdot2f(a1, w1, zb1);
      zc0 = fdot2f(b0, w0, zc0);  zc1 = fdot2f(b0, w1, zc1);
      zd0 = fdot2f(b1, w0, zd0);  zd1 = fdot2f(b1, w1, zd1);
    }
    float s0 = fmaxf(za0, 0.f) * u0 + fmaxf(za1, 0.f) * u1;
    float s1 = fmaxf(zb0, 0.f) * u0 + fmaxf(zb1, 0.f) * u1;
    float s2 = fmaxf(zc0, 0.f) * u0 + fmaxf(zc1, 0.f) * u1;
    float s3 = fmaxf(zd0, 0.f) * u0 + fmaxf(zd1, 0.f) * u1;
#pragma unroll
    for (int off = 32; off; off >>= 1) {
      s0 += __shfl_xor(s0, off, 64);
      s1 += __shfl_xor(s1, off, 64);
      s2 += __shfl_xor(s2, off, 64);
      s3 += __shfl_xor(s3, off, 64);
    }
    if (lane == 0) {
      float cc = cscal[g];
      out[row0] = s0 + cc;
      out[row0 + 1] = s1 + cc;
      out[row0 + 2] = s2 + cc;
      out[row0 + 3] = s3 + cc;
    }
  }
}

extern "C" void kernel_launch(void* const* d_in, const int* in_sizes, int n_in,
                              void* d_out, int out_size, void* d_ws, size_t ws_size,
                              hipStream_t stream) {
  const float* node_features = (const float*)d_in[0];
  const float* w_n2l        = (const float*)d_in[1];
  const float* bias_n2l     = (const float*)d_in[2];
  const float* bias_picked  = (const float*)d_in[3];
  const float* conv_W       = (const float*)d_in[4];
  const float* conv_b       = (const float*)d_in[5];
  const float* lin1_W       = (const float*)d_in[6];
  const float* lin1_b       = (const float*)d_in[7];
  const float* lout_W       = (const float*)d_in[8];
  const float* lout_b       = (const float*)d_in[9];
  const int*   edges_src    = (const int*)d_in[11];
  const int*   edges_dst    = (const int*)d_in[12];
  const int*   target_nodes = (const int*)d_in[13];
  const int*   picked_nodes = (const int*)d_in[14];
  float* q_out = (float*)d_out;

  // workspace layout
  float*  base  = (float*)d_ws;                           // N*D fp32
  __half* b16   = (__half*)(base + (size_t)Nn * Dd);      // NR*D fp16 (relu'd)
  __half* b16p  = b16 + (size_t)NR * Dd;                  // N*D fp16 (pre-relu)
  __half* hAh   = b16p + (size_t)Nn * Dd;                 // B*NR*D fp16
  __half* h2    = hAh + (size_t)Bg * NR * Dd;             // B*N*D fp16
  int*    deg   = (int*)(h2 + (size_t)Bg * Nn * Dd);      // B*N
  float*  gsum  = (float*)(deg + (size_t)Bg * Nn);        // B*64
  int*    offs  = (int*)(gsum + Bg * Dd);                 // B*N
  int*    hpart = offs + (size_t)Bg * Nn;                 // B*NCH*N (partials -> bases)
  u16*    ssrc  = (u16*)(hpart + (size_t)Bg * NCH * Nn);  // B*E u16
  float*  cvec  = (float*)(ssrc + (size_t)Bg * Eg);       // B*128
  float*  uvec  = cvec + Bg * Hh;                         // B*128
  float*  csc   = uvec + Bg * Hh;                         // B

  hipMemsetAsync(gsum, 0, (size_t)Bg * Dd * sizeof(float), stream);

  k_base<<<512, 256, 0, stream>>>(node_features, w_n2l, bias_n2l, base, b16, b16p);
  k_hist<<<NCH * Bg, 1024, 0, stream>>>(edges_dst, hpart);
  k_scan<<<Bg, 1024, 0, stream>>>(hpart, deg, offs, hAh);
  k_scatter<<<NCH * Bg, 1024, 0, stream>>>(edges_src, edges_dst, hpart, ssrc);
  k_level<true><<<2048, 256, 0, stream>>>(b16, hAh, base, b16p, conv_W, conv_b,
                                          bias_picked, picked_nodes, deg, offs,
                                          ssrc, gsum);
  k_level<false><<<2048, 256, 0, stream>>>(hAh, h2, base, b16p, conv_W, conv_b,
                                           bias_picked, picked_nodes, deg, offs,
                                           ssrc, gsum);
  k_prep<<<Bg, 128, 0, stream>>>(h2, gsum, target_nodes, lin1_W, lin1_b, lout_W,
                                 lout_b, cvec, uvec, csc);
  k_final<<<2048, 256, 0, stream>>>(h2, lin1_W, cvec, uvec, csc, q_out);
}